// Round 5
// baseline (1209.775 us; speedup 1.0000x reference)
//
#include <hip/hip_runtime.h>
#include <hip/hip_bf16.h>
#include <math.h>

// Problem constants
#define B_   4
#define S_   2048
#define D_   2048
#define H_   16
#define HD_  128
#define N3_  6144   // 3*D
#define M_   8192   // B*S

typedef __attribute__((ext_vector_type(8))) short  short8;
typedef __attribute__((ext_vector_type(4))) float  float4_;

using bf16 = __hip_bfloat16;

static __device__ __forceinline__ float bf2f(bf16 v){ return __bfloat162float(v); }
static __device__ __forceinline__ bf16  f2bf(float v){ return __float2bfloat16(v); }
static __device__ __forceinline__ short f2bfs(float v){
    return (short)__builtin_bit_cast(unsigned short, __float2bfloat16(v));
}

// load 8 elements as bf16 short8 — overloaded on source dtype
static __device__ __forceinline__ short8 load8(const bf16* p){ return *(const short8*)p; }
static __device__ __forceinline__ short8 load8(const float* p){
    float4_ a = *(const float4_*)p;
    float4_ b = *(const float4_*)(p + 4);
    short8 r;
    r[0]=f2bfs(a[0]); r[1]=f2bfs(a[1]); r[2]=f2bfs(a[2]); r[3]=f2bfs(a[3]);
    r[4]=f2bfs(b[0]); r[5]=f2bfs(b[1]); r[6]=f2bfs(b[2]); r[7]=f2bfs(b[3]);
    return r;
}

// async global->LDS 16B copy (global_load_lds_dwordx4)
static __device__ __forceinline__ void cp16_g2l(const void* g, void* l){
    __builtin_amdgcn_global_load_lds((const __attribute__((address_space(1))) void*)g,
                                     (__attribute__((address_space(3))) void*)l,
                                     16, 0, 0);
}

// ---------------- cast fp32 -> bf16 (fast path only) ----------------
__global__ void cast_f32_bf16(const float* __restrict__ in, bf16* __restrict__ out, long n8){
    long i = (long)blockIdx.x * blockDim.x + threadIdx.x;
    if (i >= n8) return;
    *((short8*)out + i) = load8(in + 8*i);
}

// ---------------- bf16 MFMA GEMM: C = A * Bt^T + bias ----------------
template<typename AT, typename BT, typename OUT_T>
__global__ __launch_bounds__(256) void gemm_bt(const AT* __restrict__ A, int lda,
                                               const BT* __restrict__ Bt, int ldb,
                                               const float* __restrict__ bias,
                                               OUT_T* __restrict__ C, int ldc, int Kdim){
    constexpr bool ASYNC = (sizeof(AT) == 2) && (sizeof(BT) == 2);
    __shared__ __align__(16) bf16 As[128*32];
    __shared__ __align__(16) bf16 Bs[128*32];
    const int tid  = threadIdx.x;
    const int lane = tid & 63;
    const int w    = tid >> 6;
    const int wm   = w >> 1, wn = w & 1;
    const int quad = lane >> 4, l15 = lane & 15;
    const int bn0  = blockIdx.x * 128, bm0 = blockIdx.y * 128;
    const int srow = tid >> 2;          // 0..63
    const int scol = (tid & 3) * 8;     // 0,8,16,24

    float4_ acc[4][4] = {};

    for (int k0 = 0; k0 < Kdim; k0 += 32){
        __syncthreads();
        if constexpr (ASYNC){
            const int cb = (tid & 3) * 16;   // byte col within 64B k-slab
            const int rr = tid >> 2;
            #pragma unroll
            for (int hf = 0; hf < 2; ++hf){
                const int r = hf*64 + rr;
                cp16_g2l((const char*)(A  + (size_t)(bm0 + r)*lda + k0) + cb, (char*)As + r*64 + cb);
                cp16_g2l((const char*)(Bt + (size_t)(bn0 + r)*ldb + k0) + cb, (char*)Bs + r*64 + cb);
            }
        } else {
            #pragma unroll
            for (int half = 0; half < 2; ++half){
                int r = half*64 + srow;
                *(short8*)&As[r*32 + scol] = load8(&A[(size_t)(bm0 + r)*lda + k0 + scol]);
                *(short8*)&Bs[r*32 + scol] = load8(&Bt[(size_t)(bn0 + r)*ldb + k0 + scol]);
            }
        }
        __syncthreads();
        short8 af[4], bfr[4];
        #pragma unroll
        for (int mt = 0; mt < 4; ++mt) af[mt]  = *(const short8*)&As[(wm*64 + mt*16 + l15)*32 + quad*8];
        #pragma unroll
        for (int nt = 0; nt < 4; ++nt) bfr[nt] = *(const short8*)&Bs[(wn*64 + nt*16 + l15)*32 + quad*8];
        #pragma unroll
        for (int mt = 0; mt < 4; ++mt)
            #pragma unroll
            for (int nt = 0; nt < 4; ++nt)
                acc[mt][nt] = __builtin_amdgcn_mfma_f32_16x16x32_bf16(af[mt], bfr[nt], acc[mt][nt], 0, 0, 0);
    }

    // epilogue: C/D layout col=lane&15, row=quad*4+reg (m89/m91 verified)
    #pragma unroll
    for (int mt = 0; mt < 4; ++mt){
        int row = bm0 + wm*64 + mt*16 + quad*4;
        #pragma unroll
        for (int nt = 0; nt < 4; ++nt){
            int col = bn0 + wn*64 + nt*16 + l15;
            float bia = bias[col];
            #pragma unroll
            for (int r = 0; r < 4; ++r){
                float v = acc[mt][nt][r] + bia;
                size_t idx = (size_t)(row + r)*ldc + col;
                if constexpr (sizeof(OUT_T) == 2) ((bf16*)C)[idx] = f2bf(v);
                else                              ((float*)C)[idx] = v;
            }
        }
    }
}

// ---------------- RoPE apply in-place on q,k inside qkv (inline trig) --------
__global__ void rope_apply(bf16* __restrict__ qkv){
    int idx = blockIdx.x * blockDim.x + threadIdx.x;  // ((b*S+s)*H + h)*64 + p
    int p = idx & 63;
    int h = (idx >> 6) & (H_-1);
    int s = (idx >> 10) & (S_-1);
    int b = idx >> 21;
    float freq = powf(10000.0f, -(float)(2*p) / (float)HD_);
    float ang = (float)s * freq;
    float c = cosf(ang), sn = sinf(ang);
    size_t base = (size_t)(b*S_ + s) * N3_ + h*HD_ + 2*p;
    float tr = bf2f(qkv[base]), ti = bf2f(qkv[base+1]);
    qkv[base]   = f2bf(tr*c - ti*sn);
    qkv[base+1] = f2bf(tr*sn + ti*c);
    size_t kb = base + D_;
    tr = bf2f(qkv[kb]); ti = bf2f(qkv[kb+1]);
    qkv[kb]   = f2bf(tr*c - ti*sn);
    qkv[kb+1] = f2bf(tr*sn + ti*c);
}

// ---------------- causal flash attention ----------------
// 512-thread blocks (8 waves x 16 q-rows = 128-row q-panel). 16 q-tiles,
// balanced pairs (tp, 15-tp): every block does exactly 34 chunks of 64 keys.
// T14 async-STAGE split: K/V for chunk c+1 are global-loaded into registers
// DURING chunk c's compute (2-set static register pipeline, nch always even),
// so HBM latency is off the per-chunk critical path. ds_writes at chunk start
// come from already-arrived regs. K swizzle (row&7)<<4; Vt transposed with
// swizzle (((d&7)^(d>>5))&7)<<4; P roundtrip per-wave [16][64] swizzled.
__global__ __launch_bounds__(512, 4) void attn(bf16* __restrict__ QKV){
    const int bid  = blockIdx.x;
    const int xcd  = bid & 7, slot = bid >> 3;
    const int bh   = xcd*8 + (slot & 7);
    const int tp   = slot >> 3;                 // 0..7
    const int b = bh >> 4, h = bh & 15;
    const int tid = threadIdx.x;
    const int w = tid >> 6, lane = tid & 63, quad = lane >> 4, l15 = lane & 15;
    bf16* Qp = QKV + (size_t)b*S_*N3_ + h*HD_;
    const bf16* Kp = Qp + D_;
    const bf16* Vp = Qp + 2*D_;
    __shared__ __align__(16) bf16 Ks[64*128];      // [key][d], XOR swizzled
    __shared__ __align__(16) bf16 Vt[128*64];      // [d][key], XOR swizzled
    __shared__ __align__(16) bf16 Pls[8*16*64];    // per-wave [16][64], XOR swz

    // staging ids: 8 lanes cover one key's 256B (32B each), 64 keys/block
    const int skey = tid >> 3;           // 0..63
    const int st   = tid & 7;            // 32B col group
    const int kswz = (skey & 7) << 4;

    const float scale2 = 0.12751707470412558f;  // (1/sqrt(128)) * log2(e)

    auto issue_loads = [&](short8 (&kr)[2], short8 (&vr)[2], int kb){
        const char* krow = (const char*)&Kp[(size_t)(kb + skey)*N3_];
        const char* vrow = (const char*)&Vp[(size_t)(kb + skey)*N3_];
        kr[0] = *(const short8*)(krow + st*32);
        kr[1] = *(const short8*)(krow + st*32 + 16);
        vr[0] = *(const short8*)(vrow + st*32);
        vr[1] = *(const short8*)(vrow + st*32 + 16);
    };
    auto stage_write = [&](const short8 (&kr)[2], const short8 (&vr)[2]){
        #pragma unroll
        for (int u = 0; u < 2; ++u)
            *(short8*)((char*)Ks + ((skey*256 + st*32 + u*16) ^ kswz)) = kr[u];
        #pragma unroll
        for (int g = 0; g < 2; ++g){
            short8 vv = vr[g];
            #pragma unroll
            for (int j = 0; j < 8; ++j){
                const int d = st*16 + g*8 + j;   // d&7==j, d>>5==st>>1
                *(short*)((char*)Vt + ((d*128 + skey*2)
                          ^ (((j ^ (st >> 1)) & 7) << 4))) = vv[j];
            }
        }
    };

    short8 kA[2], vA[2], kB[2], vB[2];
    issue_loads(kA, vA, 0);              // prologue: chunk 0 of half 0

    for (int half = 0; half < 2; ++half){
        const int t = half ? (15 - tp) : tp;
        const int qrow = t*128 + w*16 + l15;
        short8 qf[4];
        #pragma unroll
        for (int kc = 0; kc < 4; ++kc)
            qf[kc] = *(const short8*)&Qp[(size_t)qrow*N3_ + kc*32 + quad*8];

        float4_ accO[8] = {};
        float m_i[4], l_i[4];
        #pragma unroll
        for (int r = 0; r < 4; ++r){ m_i[r] = -3.0e38f; l_i[r] = 0.0f; }
        const int rbase = t*128 + w*16 + quad*4;
        const int wmax  = t*128 + w*16 + 15;
        const int nch = 2*t + 2;         // always even

        auto compute = [&](int kb){
            // ---- QK^T (16 MFMA, 4 independent chains) ----
            float4_ sacc[4] = {};
            __builtin_amdgcn_s_setprio(1);
            #pragma unroll
            for (int kc = 0; kc < 4; ++kc)
                #pragma unroll
                for (int nt = 0; nt < 4; ++nt){
                    short8 kf = *(const short8*)((const char*)Ks +
                        (((nt*16 + l15)*256 + kc*64 + quad*16) ^ ((l15 & 7) << 4)));
                    sacc[nt] = __builtin_amdgcn_mfma_f32_16x16x32_bf16(qf[kc], kf, sacc[nt], 0, 0, 0);
                }
            __builtin_amdgcn_s_setprio(0);

            // ---- scale (exp2 domain) + causal mask, in place ----
            #pragma unroll
            for (int nt = 0; nt < 4; ++nt){
                const int j = kb + nt*16 + l15;
                #pragma unroll
                for (int r = 0; r < 4; ++r){
                    float v = sacc[nt][r] * scale2;
                    sacc[nt][r] = (j > rbase + r) ? -3.0e38f : v;
                }
            }

            // ---- online softmax (reduce across the 16-lane l15 group) ----
            float alpha[4];
            #pragma unroll
            for (int r = 0; r < 4; ++r){
                float v = fmaxf(fmaxf(sacc[0][r], sacc[1][r]), fmaxf(sacc[2][r], sacc[3][r]));
                v = fmaxf(v, m_i[r]);
                #pragma unroll
                for (int off = 1; off < 16; off <<= 1) v = fmaxf(v, __shfl_xor(v, off, 64));
                alpha[r] = exp2f(m_i[r] - v);
                m_i[r] = v;
                float s = 0.0f;
                #pragma unroll
                for (int nt = 0; nt < 4; ++nt){
                    float p = exp2f(sacc[nt][r] - v);
                    sacc[nt][r] = p; s += p;
                }
                #pragma unroll
                for (int off = 1; off < 16; off <<= 1) s += __shfl_xor(s, off, 64);
                l_i[r] = l_i[r]*alpha[r] + s;
            }
            #pragma unroll
            for (int dt = 0; dt < 8; ++dt)
                #pragma unroll
                for (int r = 0; r < 4; ++r) accO[dt][r] *= alpha[r];

            // ---- P: C-layout -> per-wave LDS [16][64] XOR-swz -> A-layout ----
            #pragma unroll
            for (int nt = 0; nt < 4; ++nt)
                #pragma unroll
                for (int r = 0; r < 4; ++r){
                    const int prow = quad*4 + r;
                    *(short*)((char*)Pls + ((w*2048 + prow*128 + (nt*16 + l15)*2)
                                            ^ ((prow & 7) << 4))) = f2bfs(sacc[nt][r]);
                }
            __asm volatile("s_waitcnt lgkmcnt(0)" ::: "memory");
            short8 pf0 = *(const short8*)((const char*)Pls +
                ((w*2048 + l15*128      + quad*16) ^ ((l15 & 7) << 4)));
            short8 pf1 = *(const short8*)((const char*)Pls +
                ((w*2048 + l15*128 + 64 + quad*16) ^ ((l15 & 7) << 4)));

            // ---- PV (16 MFMA) ----
            __builtin_amdgcn_s_setprio(1);
            #pragma unroll
            for (int dt = 0; dt < 8; ++dt){
                const int rb = (dt*16 + l15)*128;
                const int sw = (((l15 & 7) ^ (dt >> 1)) & 7) << 4;
                short8 vf0 = *(const short8*)((const char*)Vt + ((rb      + quad*16) ^ sw));
                short8 vf1 = *(const short8*)((const char*)Vt + ((rb + 64 + quad*16) ^ sw));
                accO[dt] = __builtin_amdgcn_mfma_f32_16x16x32_bf16(pf0, vf0, accO[dt], 0, 0, 0);
                accO[dt] = __builtin_amdgcn_mfma_f32_16x16x32_bf16(pf1, vf1, accO[dt], 0, 0, 0);
            }
            __builtin_amdgcn_s_setprio(0);
        };

        for (int c = 0; c < nch; c += 2){
            // ---- STEP even: consume set A, prefetch c+1 into set B ----
            __syncthreads();               // WAR: prev chunk's LDS reads done
            stage_write(kA, vA);
            issue_loads(kB, vB, (c+1)*64); // hides under this chunk's compute
            __syncthreads();
            if (c*64 <= wmax) compute(c*64);

            // ---- STEP odd: consume set B, prefetch c+2 (or next half) into A ----
            __syncthreads();
            stage_write(kB, vB);
            {
                const int nkb = (c+2 < nch) ? (c+2)*64 : (half == 0 ? 0 : -1);
                if (nkb >= 0) issue_loads(kA, vA, nkb);
            }
            __syncthreads();
            if ((c+1)*64 <= wmax) compute((c+1)*64);
        }

        // ---- normalize + write O into q-slice (race-free: rows owned by block) ----
        float inv[4];
        #pragma unroll
        for (int r = 0; r < 4; ++r) inv[r] = 1.0f / l_i[r];
        #pragma unroll
        for (int dt = 0; dt < 8; ++dt)
            #pragma unroll
            for (int r = 0; r < 4; ++r){
                int s = t*128 + w*16 + quad*4 + r;
                int d = dt*16 + l15;
                Qp[(size_t)s*N3_ + d] = f2bf(accO[dt][r]*inv[r]);
            }
    }
}

// ---------------- launch ----------------
extern "C" void kernel_launch(void* const* d_in, const int* in_sizes, int n_in,
                              void* d_out, int out_size, void* d_ws, size_t ws_size,
                              hipStream_t stream){
    const float* x    = (const float*)d_in[0];
    const float* Wqkv = (const float*)d_in[1];
    const float* bqkv = (const float*)d_in[2];
    const float* Wo   = (const float*)d_in[3];
    const float* bo   = (const float*)d_in[4];
    float* out = (float*)d_out;
    char* ws = (char*)d_ws;

    // qkv is the only mandatory buffer: 8192 x 6144 bf16 = 100,663,296 B (96 MiB)
    bf16* qkv = (bf16*)(ws + 0);

    // Fast path needs additionally: xb 32 MiB + wqkvb 24 MiB + wob 8 MiB -> 160 MiB total
    const size_t OFF_XB = 100663296, OFF_WQ = 134217728, OFF_WO = 159383552;
    const bool big = (ws_size >= (size_t)167772160);

    if (big){
        bf16* xb    = (bf16*)(ws + OFF_XB);
        bf16* wqkvb = (bf16*)(ws + OFF_WQ);
        bf16* wob   = (bf16*)(ws + OFF_WO);
        long n8;
        n8 = (long)M_*D_/8;   cast_f32_bf16<<<(n8+255)/256, 256, 0, stream>>>(x, xb, n8);
        n8 = (long)N3_*D_/8;  cast_f32_bf16<<<(n8+255)/256, 256, 0, stream>>>(Wqkv, wqkvb, n8);
        n8 = (long)D_*D_/8;   cast_f32_bf16<<<(n8+255)/256, 256, 0, stream>>>(Wo, wob, n8);
        gemm_bt<bf16,bf16,bf16><<<dim3(N3_/128, M_/128), 256, 0, stream>>>(
            xb, D_, wqkvb, D_, bqkv, qkv, N3_, D_);
        rope_apply<<<(B_*S_*H_*64)/256, 256, 0, stream>>>(qkv);
        attn<<<dim3(512), 512, 0, stream>>>(qkv);
        gemm_bt<bf16,bf16,float><<<dim3(D_/128, M_/128), 256, 0, stream>>>(
            qkv, N3_, wob, D_, bo, out, D_, D_);
    } else {
        // compact path: fp32 inputs converted during GEMM staging; 96 MiB workspace
        gemm_bt<float,float,bf16><<<dim3(N3_/128, M_/128), 256, 0, stream>>>(
            x, D_, Wqkv, D_, bqkv, qkv, N3_, D_);
        rope_apply<<<(B_*S_*H_*64)/256, 256, 0, stream>>>(qkv);
        attn<<<dim3(512), 512, 0, stream>>>(qkv);
        gemm_bt<bf16,float,float><<<dim3(D_/128, M_/128), 256, 0, stream>>>(
            qkv, N3_, Wo, D_, bo, out, D_, D_);
    }
}

// Round 6
// 1193.928 us; speedup vs baseline: 1.0133x; 1.0133x over previous
//
#include <hip/hip_runtime.h>
#include <hip/hip_bf16.h>
#include <math.h>

// Problem constants
#define B_   4
#define S_   2048
#define D_   2048
#define H_   16
#define HD_  128
#define N3_  6144   // 3*D
#define M_   8192   // B*S

typedef __attribute__((ext_vector_type(8))) short  short8;
typedef __attribute__((ext_vector_type(4))) float  float4_;

using bf16 = __hip_bfloat16;

static __device__ __forceinline__ float bf2f(bf16 v){ return __bfloat162float(v); }
static __device__ __forceinline__ bf16  f2bf(float v){ return __float2bfloat16(v); }
static __device__ __forceinline__ short f2bfs(float v){
    return (short)__builtin_bit_cast(unsigned short, __float2bfloat16(v));
}

// load 8 elements as bf16 short8 — overloaded on source dtype
static __device__ __forceinline__ short8 load8(const bf16* p){ return *(const short8*)p; }
static __device__ __forceinline__ short8 load8(const float* p){
    float4_ a = *(const float4_*)p;
    float4_ b = *(const float4_*)(p + 4);
    short8 r;
    r[0]=f2bfs(a[0]); r[1]=f2bfs(a[1]); r[2]=f2bfs(a[2]); r[3]=f2bfs(a[3]);
    r[4]=f2bfs(b[0]); r[5]=f2bfs(b[1]); r[6]=f2bfs(b[2]); r[7]=f2bfs(b[3]);
    return r;
}

// async global->LDS 16B copy (global_load_lds_dwordx4)
static __device__ __forceinline__ void cp16_g2l(const void* g, void* l){
    __builtin_amdgcn_global_load_lds((const __attribute__((address_space(1))) void*)g,
                                     (__attribute__((address_space(3))) void*)l,
                                     16, 0, 0);
}

// ---------------- cast fp32 -> bf16 (fast path only) ----------------
__global__ void cast_f32_bf16(const float* __restrict__ in, bf16* __restrict__ out, long n8){
    long i = (long)blockIdx.x * blockDim.x + threadIdx.x;
    if (i >= n8) return;
    *((short8*)out + i) = load8(in + 8*i);
}

// ---------------- bf16 MFMA GEMM: C = A * Bt^T + bias ----------------
template<typename AT, typename BT, typename OUT_T>
__global__ __launch_bounds__(256) void gemm_bt(const AT* __restrict__ A, int lda,
                                               const BT* __restrict__ Bt, int ldb,
                                               const float* __restrict__ bias,
                                               OUT_T* __restrict__ C, int ldc, int Kdim){
    constexpr bool ASYNC = (sizeof(AT) == 2) && (sizeof(BT) == 2);
    __shared__ __align__(16) bf16 As[128*32];
    __shared__ __align__(16) bf16 Bs[128*32];
    const int tid  = threadIdx.x;
    const int lane = tid & 63;
    const int w    = tid >> 6;
    const int wm   = w >> 1, wn = w & 1;
    const int quad = lane >> 4, l15 = lane & 15;
    const int bn0  = blockIdx.x * 128, bm0 = blockIdx.y * 128;
    const int srow = tid >> 2;          // 0..63
    const int scol = (tid & 3) * 8;     // 0,8,16,24

    float4_ acc[4][4] = {};

    for (int k0 = 0; k0 < Kdim; k0 += 32){
        __syncthreads();
        if constexpr (ASYNC){
            const int cb = (tid & 3) * 16;   // byte col within 64B k-slab
            const int rr = tid >> 2;
            #pragma unroll
            for (int hf = 0; hf < 2; ++hf){
                const int r = hf*64 + rr;
                cp16_g2l((const char*)(A  + (size_t)(bm0 + r)*lda + k0) + cb, (char*)As + r*64 + cb);
                cp16_g2l((const char*)(Bt + (size_t)(bn0 + r)*ldb + k0) + cb, (char*)Bs + r*64 + cb);
            }
        } else {
            #pragma unroll
            for (int half = 0; half < 2; ++half){
                int r = half*64 + srow;
                *(short8*)&As[r*32 + scol] = load8(&A[(size_t)(bm0 + r)*lda + k0 + scol]);
                *(short8*)&Bs[r*32 + scol] = load8(&Bt[(size_t)(bn0 + r)*ldb + k0 + scol]);
            }
        }
        __syncthreads();
        short8 af[4], bfr[4];
        #pragma unroll
        for (int mt = 0; mt < 4; ++mt) af[mt]  = *(const short8*)&As[(wm*64 + mt*16 + l15)*32 + quad*8];
        #pragma unroll
        for (int nt = 0; nt < 4; ++nt) bfr[nt] = *(const short8*)&Bs[(wn*64 + nt*16 + l15)*32 + quad*8];
        #pragma unroll
        for (int mt = 0; mt < 4; ++mt)
            #pragma unroll
            for (int nt = 0; nt < 4; ++nt)
                acc[mt][nt] = __builtin_amdgcn_mfma_f32_16x16x32_bf16(af[mt], bfr[nt], acc[mt][nt], 0, 0, 0);
    }

    // epilogue: C/D layout col=lane&15, row=quad*4+reg (m89/m91 verified)
    #pragma unroll
    for (int mt = 0; mt < 4; ++mt){
        int row = bm0 + wm*64 + mt*16 + quad*4;
        #pragma unroll
        for (int nt = 0; nt < 4; ++nt){
            int col = bn0 + wn*64 + nt*16 + l15;
            float bia = bias[col];
            #pragma unroll
            for (int r = 0; r < 4; ++r){
                float v = acc[mt][nt][r] + bia;
                size_t idx = (size_t)(row + r)*ldc + col;
                if constexpr (sizeof(OUT_T) == 2) ((bf16*)C)[idx] = f2bf(v);
                else                              ((float*)C)[idx] = v;
            }
        }
    }
}

// ---------------- RoPE apply in-place on q,k inside qkv (inline trig) --------
__global__ void rope_apply(bf16* __restrict__ qkv){
    int idx = blockIdx.x * blockDim.x + threadIdx.x;  // ((b*S+s)*H + h)*64 + p
    int p = idx & 63;
    int h = (idx >> 6) & (H_-1);
    int s = (idx >> 10) & (S_-1);
    int b = idx >> 21;
    float freq = powf(10000.0f, -(float)(2*p) / (float)HD_);
    float ang = (float)s * freq;
    float c = cosf(ang), sn = sinf(ang);
    size_t base = (size_t)(b*S_ + s) * N3_ + h*HD_ + 2*p;
    float tr = bf2f(qkv[base]), ti = bf2f(qkv[base+1]);
    qkv[base]   = f2bf(tr*c - ti*sn);
    qkv[base+1] = f2bf(tr*sn + ti*c);
    size_t kb = base + D_;
    tr = bf2f(qkv[kb]); ti = bf2f(qkv[kb+1]);
    qkv[kb]   = f2bf(tr*c - ti*sn);
    qkv[kb+1] = f2bf(tr*sn + ti*c);
}

// prefetch register set: by-value struct (SROA-friendly; NO arrays, no by-ref
// lambda mutation — round-5's short8[2] arrays through lambda refs went to
// scratch: +700MB traffic, the regression).
struct KV { short8 k0, k1, v0, v1; };

// ---------------- causal flash attention ----------------
// 512-thread blocks (8 waves x 16 q-rows = 128-row q-panel). 16 q-tiles,
// balanced pairs (tp, 15-tp): every block does exactly 34 chunks of 64 keys.
// T14 async-STAGE: chunk c+1's K/V are global-loaded into registers during
// chunk c's compute. Half-1 iterates chunks DESCENDING: block tp then reads
// chunk s at step s (half0) / chunk 33-s (half1) independent of tp -> the 8
// tp-blocks of one bh touch <=2 distinct chunks per step -> XCD-L2 reuse
// (bh-major XCD remap keeps all 8 on one XCD).
__global__ __launch_bounds__(512, 4) void attn(bf16* __restrict__ QKV){
    const int bid  = blockIdx.x;
    const int xcd  = bid & 7, slot = bid >> 3;
    const int bh   = xcd*8 + (slot & 7);
    const int tp   = slot >> 3;                 // 0..7
    const int b = bh >> 4, h = bh & 15;
    const int tid = threadIdx.x;
    const int w = tid >> 6, lane = tid & 63, quad = lane >> 4, l15 = lane & 15;
    bf16* Qp = QKV + (size_t)b*S_*N3_ + h*HD_;
    const bf16* Kp = Qp + D_;
    const bf16* Vp = Qp + 2*D_;
    __shared__ __align__(16) bf16 Ks[64*128];      // [key][d], XOR swizzled
    __shared__ __align__(16) bf16 Vt[128*64];      // [d][key], XOR swizzled
    __shared__ __align__(16) bf16 Pls[8*16*64];    // per-wave [16][64], XOR swz

    // staging ids: 8 lanes cover one key's 256B (32B each), 64 keys/block
    const int skey = tid >> 3;           // 0..63
    const int st   = tid & 7;            // 32B col group
    const int kswz = (skey & 7) << 4;

    const float scale2 = 0.12751707470412558f;  // (1/sqrt(128)) * log2(e)

    auto load_kv = [&](int kb) -> KV {
        KV r;
        const char* krow = (const char*)&Kp[(size_t)(kb + skey)*N3_];
        const char* vrow = (const char*)&Vp[(size_t)(kb + skey)*N3_];
        r.k0 = *(const short8*)(krow + st*32);
        r.k1 = *(const short8*)(krow + st*32 + 16);
        r.v0 = *(const short8*)(vrow + st*32);
        r.v1 = *(const short8*)(vrow + st*32 + 16);
        return r;
    };
    auto stage_write = [&](KV x){
        *(short8*)((char*)Ks + ((skey*256 + st*32     ) ^ kswz)) = x.k0;
        *(short8*)((char*)Ks + ((skey*256 + st*32 + 16) ^ kswz)) = x.k1;
        #pragma unroll
        for (int g = 0; g < 2; ++g){
            short8 vv = g ? x.v1 : x.v0;
            #pragma unroll
            for (int j = 0; j < 8; ++j){
                const int d = st*16 + g*8 + j;   // d&7==j, d>>5==st>>1
                *(short*)((char*)Vt + ((d*128 + skey*2)
                          ^ (((j ^ (st >> 1)) & 7) << 4))) = vv[j];
            }
        }
    };

    KV a = load_kv(0);                   // prologue: chunk 0 of half 0
    KV bset;

    for (int half = 0; half < 2; ++half){
        const int t = half ? (15 - tp) : tp;
        const int qrow = t*128 + w*16 + l15;
        short8 qf[4];
        #pragma unroll
        for (int kc = 0; kc < 4; ++kc)
            qf[kc] = *(const short8*)&Qp[(size_t)qrow*N3_ + kc*32 + quad*8];

        float4_ accO[8] = {};
        float m_i[4], l_i[4];
        #pragma unroll
        for (int r = 0; r < 4; ++r){ m_i[r] = -3.0e38f; l_i[r] = 0.0f; }
        const int rbase = t*128 + w*16 + quad*4;
        const int wmax  = t*128 + w*16 + 15;
        const int nch = 2*t + 2;         // always even
        const int nch1 = 32 - 2*tp;      // half-1 chunk count (for transition)
        // chunk of step s: ascending in half 0, descending in half 1
        auto kb_of = [&](int s){ return (half ? (nch - 1 - s) : s) * 64; };

        auto compute = [&](int kb){
            // ---- QK^T (16 MFMA, 4 independent chains) ----
            float4_ sacc[4] = {};
            __builtin_amdgcn_s_setprio(1);
            #pragma unroll
            for (int kc = 0; kc < 4; ++kc)
                #pragma unroll
                for (int nt = 0; nt < 4; ++nt){
                    short8 kf = *(const short8*)((const char*)Ks +
                        (((nt*16 + l15)*256 + kc*64 + quad*16) ^ ((l15 & 7) << 4)));
                    sacc[nt] = __builtin_amdgcn_mfma_f32_16x16x32_bf16(qf[kc], kf, sacc[nt], 0, 0, 0);
                }
            __builtin_amdgcn_s_setprio(0);

            // ---- scale (exp2 domain) + causal mask, in place ----
            #pragma unroll
            for (int nt = 0; nt < 4; ++nt){
                const int j = kb + nt*16 + l15;
                #pragma unroll
                for (int r = 0; r < 4; ++r){
                    float v = sacc[nt][r] * scale2;
                    sacc[nt][r] = (j > rbase + r) ? -3.0e38f : v;
                }
            }

            // ---- online softmax (reduce across the 16-lane l15 group) ----
            float alpha[4];
            #pragma unroll
            for (int r = 0; r < 4; ++r){
                float v = fmaxf(fmaxf(sacc[0][r], sacc[1][r]), fmaxf(sacc[2][r], sacc[3][r]));
                v = fmaxf(v, m_i[r]);
                #pragma unroll
                for (int off = 1; off < 16; off <<= 1) v = fmaxf(v, __shfl_xor(v, off, 64));
                alpha[r] = exp2f(m_i[r] - v);
                m_i[r] = v;
                float s = 0.0f;
                #pragma unroll
                for (int nt = 0; nt < 4; ++nt){
                    float p = exp2f(sacc[nt][r] - v);
                    sacc[nt][r] = p; s += p;
                }
                #pragma unroll
                for (int off = 1; off < 16; off <<= 1) s += __shfl_xor(s, off, 64);
                l_i[r] = l_i[r]*alpha[r] + s;
            }
            #pragma unroll
            for (int dt = 0; dt < 8; ++dt)
                #pragma unroll
                for (int r = 0; r < 4; ++r) accO[dt][r] *= alpha[r];

            // ---- P: C-layout -> per-wave LDS [16][64] XOR-swz -> A-layout ----
            #pragma unroll
            for (int nt = 0; nt < 4; ++nt)
                #pragma unroll
                for (int r = 0; r < 4; ++r){
                    const int prow = quad*4 + r;
                    *(short*)((char*)Pls + ((w*2048 + prow*128 + (nt*16 + l15)*2)
                                            ^ ((prow & 7) << 4))) = f2bfs(sacc[nt][r]);
                }
            __asm volatile("s_waitcnt lgkmcnt(0)" ::: "memory");
            short8 pf0 = *(const short8*)((const char*)Pls +
                ((w*2048 + l15*128      + quad*16) ^ ((l15 & 7) << 4)));
            short8 pf1 = *(const short8*)((const char*)Pls +
                ((w*2048 + l15*128 + 64 + quad*16) ^ ((l15 & 7) << 4)));

            // ---- PV (16 MFMA) ----
            __builtin_amdgcn_s_setprio(1);
            #pragma unroll
            for (int dt = 0; dt < 8; ++dt){
                const int rb = (dt*16 + l15)*128;
                const int sw = (((l15 & 7) ^ (dt >> 1)) & 7) << 4;
                short8 vf0 = *(const short8*)((const char*)Vt + ((rb      + quad*16) ^ sw));
                short8 vf1 = *(const short8*)((const char*)Vt + ((rb + 64 + quad*16) ^ sw));
                accO[dt] = __builtin_amdgcn_mfma_f32_16x16x32_bf16(pf0, vf0, accO[dt], 0, 0, 0);
                accO[dt] = __builtin_amdgcn_mfma_f32_16x16x32_bf16(pf1, vf1, accO[dt], 0, 0, 0);
            }
            __builtin_amdgcn_s_setprio(0);
        };

        for (int s = 0; s < nch; s += 2){
            // ---- STEP even: consume set a, prefetch step s+1 into bset ----
            __syncthreads();               // WAR: prev chunk's LDS reads done
            stage_write(a);
            bset = load_kv(kb_of(s + 1));  // rides under this chunk's compute
            __syncthreads();
            { const int kb0 = kb_of(s); if (kb0 <= wmax) compute(kb0); }

            // ---- STEP odd: consume bset, prefetch step s+2 (or next half) ----
            __syncthreads();
            stage_write(bset);
            if (s + 2 < nch)      a = load_kv(kb_of(s + 2));
            else if (half == 0)   a = load_kv((nch1 - 1) * 64);  // half1 starts high
            __syncthreads();
            { const int kb1 = kb_of(s + 1); if (kb1 <= wmax) compute(kb1); }
        }

        // ---- normalize + write O into q-slice (race-free: rows owned by block) ----
        float inv[4];
        #pragma unroll
        for (int r = 0; r < 4; ++r) inv[r] = 1.0f / l_i[r];
        #pragma unroll
        for (int dt = 0; dt < 8; ++dt)
            #pragma unroll
            for (int r = 0; r < 4; ++r){
                int s = t*128 + w*16 + quad*4 + r;
                int d = dt*16 + l15;
                Qp[(size_t)s*N3_ + d] = f2bf(accO[dt][r]*inv[r]);
            }
    }
}

// ---------------- launch ----------------
extern "C" void kernel_launch(void* const* d_in, const int* in_sizes, int n_in,
                              void* d_out, int out_size, void* d_ws, size_t ws_size,
                              hipStream_t stream){
    const float* x    = (const float*)d_in[0];
    const float* Wqkv = (const float*)d_in[1];
    const float* bqkv = (const float*)d_in[2];
    const float* Wo   = (const float*)d_in[3];
    const float* bo   = (const float*)d_in[4];
    float* out = (float*)d_out;
    char* ws = (char*)d_ws;

    // qkv is the only mandatory buffer: 8192 x 6144 bf16 = 100,663,296 B (96 MiB)
    bf16* qkv = (bf16*)(ws + 0);

    // Fast path needs additionally: xb 32 MiB + wqkvb 24 MiB + wob 8 MiB -> 160 MiB total
    const size_t OFF_XB = 100663296, OFF_WQ = 134217728, OFF_WO = 159383552;
    const bool big = (ws_size >= (size_t)167772160);

    if (big){
        bf16* xb    = (bf16*)(ws + OFF_XB);
        bf16* wqkvb = (bf16*)(ws + OFF_WQ);
        bf16* wob   = (bf16*)(ws + OFF_WO);
        long n8;
        n8 = (long)M_*D_/8;   cast_f32_bf16<<<(n8+255)/256, 256, 0, stream>>>(x, xb, n8);
        n8 = (long)N3_*D_/8;  cast_f32_bf16<<<(n8+255)/256, 256, 0, stream>>>(Wqkv, wqkvb, n8);
        n8 = (long)D_*D_/8;   cast_f32_bf16<<<(n8+255)/256, 256, 0, stream>>>(Wo, wob, n8);
        gemm_bt<bf16,bf16,bf16><<<dim3(N3_/128, M_/128), 256, 0, stream>>>(
            xb, D_, wqkvb, D_, bqkv, qkv, N3_, D_);
        rope_apply<<<(B_*S_*H_*64)/256, 256, 0, stream>>>(qkv);
        attn<<<dim3(512), 512, 0, stream>>>(qkv);
        gemm_bt<bf16,bf16,float><<<dim3(D_/128, M_/128), 256, 0, stream>>>(
            qkv, N3_, wob, D_, bo, out, D_, D_);
    } else {
        // compact path: fp32 inputs converted during GEMM staging; 96 MiB workspace
        gemm_bt<float,float,bf16><<<dim3(N3_/128, M_/128), 256, 0, stream>>>(
            x, D_, Wqkv, D_, bqkv, qkv, N3_, D_);
        rope_apply<<<(B_*S_*H_*64)/256, 256, 0, stream>>>(qkv);
        attn<<<dim3(512), 512, 0, stream>>>(qkv);
        gemm_bt<bf16,float,float><<<dim3(D_/128, M_/128), 256, 0, stream>>>(
            qkv, N3_, Wo, D_, bo, out, D_, D_);
    }
}

// Round 7
// 761.106 us; speedup vs baseline: 1.5895x; 1.5687x over previous
//
#include <hip/hip_runtime.h>
#include <hip/hip_bf16.h>
#include <math.h>

// Problem constants
#define B_   4
#define S_   2048
#define D_   2048
#define H_   16
#define HD_  128
#define N3_  6144   // 3*D
#define M_   8192   // B*S

typedef __attribute__((ext_vector_type(8))) short  short8;
typedef __attribute__((ext_vector_type(4))) float  float4_;

using bf16 = __hip_bfloat16;

static __device__ __forceinline__ float bf2f(bf16 v){ return __bfloat162float(v); }
static __device__ __forceinline__ bf16  f2bf(float v){ return __float2bfloat16(v); }
static __device__ __forceinline__ short f2bfs(float v){
    return (short)__builtin_bit_cast(unsigned short, __float2bfloat16(v));
}

// load 8 elements as bf16 short8 — overloaded on source dtype
static __device__ __forceinline__ short8 load8(const bf16* p){ return *(const short8*)p; }
static __device__ __forceinline__ short8 load8(const float* p){
    float4_ a = *(const float4_*)p;
    float4_ b = *(const float4_*)(p + 4);
    short8 r;
    r[0]=f2bfs(a[0]); r[1]=f2bfs(a[1]); r[2]=f2bfs(a[2]); r[3]=f2bfs(a[3]);
    r[4]=f2bfs(b[0]); r[5]=f2bfs(b[1]); r[6]=f2bfs(b[2]); r[7]=f2bfs(b[3]);
    return r;
}

// async global->LDS 16B copy (global_load_lds_dwordx4)
static __device__ __forceinline__ void cp16_g2l(const void* g, void* l){
    __builtin_amdgcn_global_load_lds((const __attribute__((address_space(1))) void*)g,
                                     (__attribute__((address_space(3))) void*)l,
                                     16, 0, 0);
}

// ---------------- cast fp32 -> bf16 (fast path only) ----------------
__global__ void cast_f32_bf16(const float* __restrict__ in, bf16* __restrict__ out, long n8){
    long i = (long)blockIdx.x * blockDim.x + threadIdx.x;
    if (i >= n8) return;
    *((short8*)out + i) = load8(in + 8*i);
}

// ---------------- bf16 MFMA GEMM: C = A * Bt^T + bias ----------------
template<typename AT, typename BT, typename OUT_T>
__global__ __launch_bounds__(256) void gemm_bt(const AT* __restrict__ A, int lda,
                                               const BT* __restrict__ Bt, int ldb,
                                               const float* __restrict__ bias,
                                               OUT_T* __restrict__ C, int ldc, int Kdim){
    constexpr bool ASYNC = (sizeof(AT) == 2) && (sizeof(BT) == 2);
    __shared__ __align__(16) bf16 As[128*32];
    __shared__ __align__(16) bf16 Bs[128*32];
    const int tid  = threadIdx.x;
    const int lane = tid & 63;
    const int w    = tid >> 6;
    const int wm   = w >> 1, wn = w & 1;
    const int quad = lane >> 4, l15 = lane & 15;
    const int bn0  = blockIdx.x * 128, bm0 = blockIdx.y * 128;
    const int srow = tid >> 2;          // 0..63
    const int scol = (tid & 3) * 8;     // 0,8,16,24

    float4_ acc[4][4] = {};

    for (int k0 = 0; k0 < Kdim; k0 += 32){
        __syncthreads();
        if constexpr (ASYNC){
            const int cb = (tid & 3) * 16;   // byte col within 64B k-slab
            const int rr = tid >> 2;
            #pragma unroll
            for (int hf = 0; hf < 2; ++hf){
                const int r = hf*64 + rr;
                cp16_g2l((const char*)(A  + (size_t)(bm0 + r)*lda + k0) + cb, (char*)As + r*64 + cb);
                cp16_g2l((const char*)(Bt + (size_t)(bn0 + r)*ldb + k0) + cb, (char*)Bs + r*64 + cb);
            }
        } else {
            #pragma unroll
            for (int half = 0; half < 2; ++half){
                int r = half*64 + srow;
                *(short8*)&As[r*32 + scol] = load8(&A[(size_t)(bm0 + r)*lda + k0 + scol]);
                *(short8*)&Bs[r*32 + scol] = load8(&Bt[(size_t)(bn0 + r)*ldb + k0 + scol]);
            }
        }
        __syncthreads();
        short8 af[4], bfr[4];
        #pragma unroll
        for (int mt = 0; mt < 4; ++mt) af[mt]  = *(const short8*)&As[(wm*64 + mt*16 + l15)*32 + quad*8];
        #pragma unroll
        for (int nt = 0; nt < 4; ++nt) bfr[nt] = *(const short8*)&Bs[(wn*64 + nt*16 + l15)*32 + quad*8];
        #pragma unroll
        for (int mt = 0; mt < 4; ++mt)
            #pragma unroll
            for (int nt = 0; nt < 4; ++nt)
                acc[mt][nt] = __builtin_amdgcn_mfma_f32_16x16x32_bf16(af[mt], bfr[nt], acc[mt][nt], 0, 0, 0);
    }

    // epilogue: C/D layout col=lane&15, row=quad*4+reg (m89/m91 verified)
    #pragma unroll
    for (int mt = 0; mt < 4; ++mt){
        int row = bm0 + wm*64 + mt*16 + quad*4;
        #pragma unroll
        for (int nt = 0; nt < 4; ++nt){
            int col = bn0 + wn*64 + nt*16 + l15;
            float bia = bias[col];
            #pragma unroll
            for (int r = 0; r < 4; ++r){
                float v = acc[mt][nt][r] + bia;
                size_t idx = (size_t)(row + r)*ldc + col;
                if constexpr (sizeof(OUT_T) == 2) ((bf16*)C)[idx] = f2bf(v);
                else                              ((float*)C)[idx] = v;
            }
        }
    }
}

// ---------------- RoPE apply in-place on q,k inside qkv (inline trig) --------
__global__ void rope_apply(bf16* __restrict__ qkv){
    int idx = blockIdx.x * blockDim.x + threadIdx.x;  // ((b*S+s)*H + h)*64 + p
    int p = idx & 63;
    int h = (idx >> 6) & (H_-1);
    int s = (idx >> 10) & (S_-1);
    int b = idx >> 21;
    float freq = powf(10000.0f, -(float)(2*p) / (float)HD_);
    float ang = (float)s * freq;
    float c = cosf(ang), sn = sinf(ang);
    size_t base = (size_t)(b*S_ + s) * N3_ + h*HD_ + 2*p;
    float tr = bf2f(qkv[base]), ti = bf2f(qkv[base+1]);
    qkv[base]   = f2bf(tr*c - ti*sn);
    qkv[base+1] = f2bf(tr*sn + ti*c);
    size_t kb = base + D_;
    tr = bf2f(qkv[kb]); ti = bf2f(qkv[kb+1]);
    qkv[kb]   = f2bf(tr*c - ti*sn);
    qkv[kb+1] = f2bf(tr*sn + ti*c);
}

// prefetch register set: by-value struct (SROA-friendly)
struct KV { short8 k0, k1, v0, v1; };

// ---------------- causal flash attention ----------------
// 512-thread blocks (8 waves x 16 q-rows = 128-row q-panel). 16 q-tiles,
// balanced pairs (tp, 15-tp): every block does exactly 34 chunks of 64 keys.
// LAUNCH BOUNDS (512,2): 2 blocks/CU (the LDS-limited residency we actually
// get) -> VGPR cap 128, not 64. Rounds 4-6 used (512,4) -> cap 64 -> the
// 32-reg KV prefetch spilled to scratch (+700MB traffic). With 128 regs the
// T14 async-STAGE pipeline is real: chunk c+1's K/V global loads ride in
// registers under chunk c's compute. Half-1 iterates chunks DESCENDING so
// the 8 tp-blocks of one bh read the same chunk at the same step (XCD-L2
// reuse; bh-major XCD remap pins all 8 to one XCD).
__global__ __launch_bounds__(512, 2) void attn(bf16* __restrict__ QKV){
    const int bid  = blockIdx.x;
    const int xcd  = bid & 7, slot = bid >> 3;
    const int bh   = xcd*8 + (slot & 7);
    const int tp   = slot >> 3;                 // 0..7
    const int b = bh >> 4, h = bh & 15;
    const int tid = threadIdx.x;
    const int w = tid >> 6, lane = tid & 63, quad = lane >> 4, l15 = lane & 15;
    bf16* Qp = QKV + (size_t)b*S_*N3_ + h*HD_;
    const bf16* Kp = Qp + D_;
    const bf16* Vp = Qp + 2*D_;
    __shared__ __align__(16) bf16 Ks[64*128];      // [key][d], XOR swizzled
    __shared__ __align__(16) bf16 Vt[128*64];      // [d][key], XOR swizzled
    __shared__ __align__(16) bf16 Pls[8*16*64];    // per-wave [16][64], XOR swz

    // staging ids: 8 lanes cover one key's 256B (32B each), 64 keys/block
    const int skey = tid >> 3;           // 0..63
    const int st   = tid & 7;            // 32B col group
    const int kswz = (skey & 7) << 4;

    const float scale2 = 0.12751707470412558f;  // (1/sqrt(128)) * log2(e)

    auto load_kv = [&](int kb) -> KV {
        KV r;
        const char* krow = (const char*)&Kp[(size_t)(kb + skey)*N3_];
        const char* vrow = (const char*)&Vp[(size_t)(kb + skey)*N3_];
        r.k0 = *(const short8*)(krow + st*32);
        r.k1 = *(const short8*)(krow + st*32 + 16);
        r.v0 = *(const short8*)(vrow + st*32);
        r.v1 = *(const short8*)(vrow + st*32 + 16);
        return r;
    };
    auto stage_write = [&](KV x){
        *(short8*)((char*)Ks + ((skey*256 + st*32     ) ^ kswz)) = x.k0;
        *(short8*)((char*)Ks + ((skey*256 + st*32 + 16) ^ kswz)) = x.k1;
        #pragma unroll
        for (int g = 0; g < 2; ++g){
            short8 vv = g ? x.v1 : x.v0;
            #pragma unroll
            for (int j = 0; j < 8; ++j){
                const int d = st*16 + g*8 + j;   // d&7==j, d>>5==st>>1
                *(short*)((char*)Vt + ((d*128 + skey*2)
                          ^ (((j ^ (st >> 1)) & 7) << 4))) = vv[j];
            }
        }
    };

    KV a = load_kv(0);                   // prologue: chunk 0 of half 0
    KV bset;

    for (int half = 0; half < 2; ++half){
        const int t = half ? (15 - tp) : tp;
        const int qrow = t*128 + w*16 + l15;
        short8 qf[4];
        #pragma unroll
        for (int kc = 0; kc < 4; ++kc)
            qf[kc] = *(const short8*)&Qp[(size_t)qrow*N3_ + kc*32 + quad*8];

        float4_ accO[8] = {};
        float m_i[4], l_i[4];
        #pragma unroll
        for (int r = 0; r < 4; ++r){ m_i[r] = -3.0e38f; l_i[r] = 0.0f; }
        const int rbase = t*128 + w*16 + quad*4;
        const int wmax  = t*128 + w*16 + 15;
        const int nch = 2*t + 2;         // always even
        const int nch1 = 32 - 2*tp;      // half-1 chunk count (for transition)
        // chunk of step s: ascending in half 0, descending in half 1
        auto kb_of = [&](int s){ return (half ? (nch - 1 - s) : s) * 64; };

        auto compute = [&](int kb){
            // ---- QK^T (16 MFMA, 4 independent chains) ----
            float4_ sacc[4] = {};
            __builtin_amdgcn_s_setprio(1);
            #pragma unroll
            for (int kc = 0; kc < 4; ++kc)
                #pragma unroll
                for (int nt = 0; nt < 4; ++nt){
                    short8 kf = *(const short8*)((const char*)Ks +
                        (((nt*16 + l15)*256 + kc*64 + quad*16) ^ ((l15 & 7) << 4)));
                    sacc[nt] = __builtin_amdgcn_mfma_f32_16x16x32_bf16(qf[kc], kf, sacc[nt], 0, 0, 0);
                }
            __builtin_amdgcn_s_setprio(0);

            // ---- scale (exp2 domain) + causal mask, in place ----
            #pragma unroll
            for (int nt = 0; nt < 4; ++nt){
                const int j = kb + nt*16 + l15;
                #pragma unroll
                for (int r = 0; r < 4; ++r){
                    float v = sacc[nt][r] * scale2;
                    sacc[nt][r] = (j > rbase + r) ? -3.0e38f : v;
                }
            }

            // ---- online softmax (reduce across the 16-lane l15 group) ----
            float alpha[4];
            #pragma unroll
            for (int r = 0; r < 4; ++r){
                float v = fmaxf(fmaxf(sacc[0][r], sacc[1][r]), fmaxf(sacc[2][r], sacc[3][r]));
                v = fmaxf(v, m_i[r]);
                #pragma unroll
                for (int off = 1; off < 16; off <<= 1) v = fmaxf(v, __shfl_xor(v, off, 64));
                alpha[r] = exp2f(m_i[r] - v);
                m_i[r] = v;
                float s = 0.0f;
                #pragma unroll
                for (int nt = 0; nt < 4; ++nt){
                    float p = exp2f(sacc[nt][r] - v);
                    sacc[nt][r] = p; s += p;
                }
                #pragma unroll
                for (int off = 1; off < 16; off <<= 1) s += __shfl_xor(s, off, 64);
                l_i[r] = l_i[r]*alpha[r] + s;
            }
            #pragma unroll
            for (int dt = 0; dt < 8; ++dt)
                #pragma unroll
                for (int r = 0; r < 4; ++r) accO[dt][r] *= alpha[r];

            // ---- P: C-layout -> per-wave LDS [16][64] XOR-swz -> A-layout ----
            #pragma unroll
            for (int nt = 0; nt < 4; ++nt)
                #pragma unroll
                for (int r = 0; r < 4; ++r){
                    const int prow = quad*4 + r;
                    *(short*)((char*)Pls + ((w*2048 + prow*128 + (nt*16 + l15)*2)
                                            ^ ((prow & 7) << 4))) = f2bfs(sacc[nt][r]);
                }
            __asm volatile("s_waitcnt lgkmcnt(0)" ::: "memory");
            short8 pf0 = *(const short8*)((const char*)Pls +
                ((w*2048 + l15*128      + quad*16) ^ ((l15 & 7) << 4)));
            short8 pf1 = *(const short8*)((const char*)Pls +
                ((w*2048 + l15*128 + 64 + quad*16) ^ ((l15 & 7) << 4)));

            // ---- PV (16 MFMA) ----
            __builtin_amdgcn_s_setprio(1);
            #pragma unroll
            for (int dt = 0; dt < 8; ++dt){
                const int rb = (dt*16 + l15)*128;
                const int sw = (((l15 & 7) ^ (dt >> 1)) & 7) << 4;
                short8 vf0 = *(const short8*)((const char*)Vt + ((rb      + quad*16) ^ sw));
                short8 vf1 = *(const short8*)((const char*)Vt + ((rb + 64 + quad*16) ^ sw));
                accO[dt] = __builtin_amdgcn_mfma_f32_16x16x32_bf16(pf0, vf0, accO[dt], 0, 0, 0);
                accO[dt] = __builtin_amdgcn_mfma_f32_16x16x32_bf16(pf1, vf1, accO[dt], 0, 0, 0);
            }
            __builtin_amdgcn_s_setprio(0);
        };

        for (int s = 0; s < nch; s += 2){
            // ---- STEP even: consume set a, prefetch step s+1 into bset ----
            __syncthreads();               // WAR: prev chunk's LDS reads done
            stage_write(a);
            bset = load_kv(kb_of(s + 1));  // rides under this chunk's compute
            __syncthreads();
            { const int kb0 = kb_of(s); if (kb0 <= wmax) compute(kb0); }

            // ---- STEP odd: consume bset, prefetch step s+2 (or next half) ----
            __syncthreads();
            stage_write(bset);
            if (s + 2 < nch)      a = load_kv(kb_of(s + 2));
            else if (half == 0)   a = load_kv((nch1 - 1) * 64);  // half1 starts high
            __syncthreads();
            { const int kb1 = kb_of(s + 1); if (kb1 <= wmax) compute(kb1); }
        }

        // ---- normalize + write O into q-slice (race-free: rows owned by block) ----
        float inv[4];
        #pragma unroll
        for (int r = 0; r < 4; ++r) inv[r] = 1.0f / l_i[r];
        #pragma unroll
        for (int dt = 0; dt < 8; ++dt)
            #pragma unroll
            for (int r = 0; r < 4; ++r){
                int s = t*128 + w*16 + quad*4 + r;
                int d = dt*16 + l15;
                Qp[(size_t)s*N3_ + d] = f2bf(accO[dt][r]*inv[r]);
            }
    }
}

// ---------------- launch ----------------
extern "C" void kernel_launch(void* const* d_in, const int* in_sizes, int n_in,
                              void* d_out, int out_size, void* d_ws, size_t ws_size,
                              hipStream_t stream){
    const float* x    = (const float*)d_in[0];
    const float* Wqkv = (const float*)d_in[1];
    const float* bqkv = (const float*)d_in[2];
    const float* Wo   = (const float*)d_in[3];
    const float* bo   = (const float*)d_in[4];
    float* out = (float*)d_out;
    char* ws = (char*)d_ws;

    // qkv is the only mandatory buffer: 8192 x 6144 bf16 = 100,663,296 B (96 MiB)
    bf16* qkv = (bf16*)(ws + 0);

    // Fast path needs additionally: xb 32 MiB + wqkvb 24 MiB + wob 8 MiB -> 160 MiB total
    const size_t OFF_XB = 100663296, OFF_WQ = 134217728, OFF_WO = 159383552;
    const bool big = (ws_size >= (size_t)167772160);

    if (big){
        bf16* xb    = (bf16*)(ws + OFF_XB);
        bf16* wqkvb = (bf16*)(ws + OFF_WQ);
        bf16* wob   = (bf16*)(ws + OFF_WO);
        long n8;
        n8 = (long)M_*D_/8;   cast_f32_bf16<<<(n8+255)/256, 256, 0, stream>>>(x, xb, n8);
        n8 = (long)N3_*D_/8;  cast_f32_bf16<<<(n8+255)/256, 256, 0, stream>>>(Wqkv, wqkvb, n8);
        n8 = (long)D_*D_/8;   cast_f32_bf16<<<(n8+255)/256, 256, 0, stream>>>(Wo, wob, n8);
        gemm_bt<bf16,bf16,bf16><<<dim3(N3_/128, M_/128), 256, 0, stream>>>(
            xb, D_, wqkvb, D_, bqkv, qkv, N3_, D_);
        rope_apply<<<(B_*S_*H_*64)/256, 256, 0, stream>>>(qkv);
        attn<<<dim3(512), 512, 0, stream>>>(qkv);
        gemm_bt<bf16,bf16,float><<<dim3(D_/128, M_/128), 256, 0, stream>>>(
            qkv, N3_, wob, D_, bo, out, D_, D_);
    } else {
        // compact path: fp32 inputs converted during GEMM staging; 96 MiB workspace
        gemm_bt<float,float,bf16><<<dim3(N3_/128, M_/128), 256, 0, stream>>>(
            x, D_, Wqkv, D_, bqkv, qkv, N3_, D_);
        rope_apply<<<(B_*S_*H_*64)/256, 256, 0, stream>>>(qkv);
        attn<<<dim3(512), 512, 0, stream>>>(qkv);
        gemm_bt<bf16,float,float><<<dim3(D_/128, M_/128), 256, 0, stream>>>(
            qkv, N3_, Wo, D_, bo, out, D_, D_);
    }
}

// Round 8
// 651.871 us; speedup vs baseline: 1.8558x; 1.1676x over previous
//
#include <hip/hip_runtime.h>
#include <hip/hip_bf16.h>
#include <math.h>

// Problem constants
#define B_   4
#define S_   2048
#define D_   2048
#define H_   16
#define HD_  128
#define N3_  6144   // 3*D
#define M_   8192   // B*S

typedef __attribute__((ext_vector_type(8))) short  short8;
typedef __attribute__((ext_vector_type(4))) float  float4_;

using bf16 = __hip_bfloat16;

static __device__ __forceinline__ float bf2f(bf16 v){ return __bfloat162float(v); }
static __device__ __forceinline__ bf16  f2bf(float v){ return __float2bfloat16(v); }
static __device__ __forceinline__ short f2bfs(float v){
    return (short)__builtin_bit_cast(unsigned short, __float2bfloat16(v));
}

// load 8 elements as bf16 short8 — overloaded on source dtype
static __device__ __forceinline__ short8 load8(const bf16* p){ return *(const short8*)p; }
static __device__ __forceinline__ short8 load8(const float* p){
    float4_ a = *(const float4_*)p;
    float4_ b = *(const float4_*)(p + 4);
    short8 r;
    r[0]=f2bfs(a[0]); r[1]=f2bfs(a[1]); r[2]=f2bfs(a[2]); r[3]=f2bfs(a[3]);
    r[4]=f2bfs(b[0]); r[5]=f2bfs(b[1]); r[6]=f2bfs(b[2]); r[7]=f2bfs(b[3]);
    return r;
}

// async global->LDS 16B copy (global_load_lds_dwordx4)
static __device__ __forceinline__ void cp16_g2l(const void* g, void* l){
    __builtin_amdgcn_global_load_lds((const __attribute__((address_space(1))) void*)g,
                                     (__attribute__((address_space(3))) void*)l,
                                     16, 0, 0);
}

#define MFMA16 __builtin_amdgcn_mfma_f32_16x16x32_bf16

// ---------------- cast fp32 -> bf16 (fast path only) ----------------
__global__ void cast_f32_bf16(const float* __restrict__ in, bf16* __restrict__ out, long n8){
    long i = (long)blockIdx.x * blockDim.x + threadIdx.x;
    if (i >= n8) return;
    *((short8*)out + i) = load8(in + 8*i);
}

// ---------------- legacy 128-tile GEMM (compact path only) ----------------
template<typename AT, typename BT, typename OUT_T>
__global__ __launch_bounds__(256) void gemm_bt(const AT* __restrict__ A, int lda,
                                               const BT* __restrict__ Bt, int ldb,
                                               const float* __restrict__ bias,
                                               OUT_T* __restrict__ C, int ldc, int Kdim){
    __shared__ __align__(16) bf16 As[128*32];
    __shared__ __align__(16) bf16 Bs[128*32];
    const int tid  = threadIdx.x;
    const int lane = tid & 63;
    const int w    = tid >> 6;
    const int wm   = w >> 1, wn = w & 1;
    const int quad = lane >> 4, l15 = lane & 15;
    const int bn0  = blockIdx.x * 128, bm0 = blockIdx.y * 128;
    const int srow = tid >> 2;          // 0..63
    const int scol = (tid & 3) * 8;     // 0,8,16,24

    float4_ acc[4][4] = {};

    for (int k0 = 0; k0 < Kdim; k0 += 32){
        __syncthreads();
        #pragma unroll
        for (int half = 0; half < 2; ++half){
            int r = half*64 + srow;
            *(short8*)&As[r*32 + scol] = load8(&A[(size_t)(bm0 + r)*lda + k0 + scol]);
            *(short8*)&Bs[r*32 + scol] = load8(&Bt[(size_t)(bn0 + r)*ldb + k0 + scol]);
        }
        __syncthreads();
        short8 af[4], bfr[4];
        #pragma unroll
        for (int mt = 0; mt < 4; ++mt) af[mt]  = *(const short8*)&As[(wm*64 + mt*16 + l15)*32 + quad*8];
        #pragma unroll
        for (int nt = 0; nt < 4; ++nt) bfr[nt] = *(const short8*)&Bs[(wn*64 + nt*16 + l15)*32 + quad*8];
        #pragma unroll
        for (int mt = 0; mt < 4; ++mt)
            #pragma unroll
            for (int nt = 0; nt < 4; ++nt)
                acc[mt][nt] = MFMA16(af[mt], bfr[nt], acc[mt][nt], 0, 0, 0);
    }

    #pragma unroll
    for (int mt = 0; mt < 4; ++mt){
        int row = bm0 + wm*64 + mt*16 + quad*4;
        #pragma unroll
        for (int nt = 0; nt < 4; ++nt){
            int col = bn0 + wn*64 + nt*16 + l15;
            float bia = bias[col];
            #pragma unroll
            for (int r = 0; r < 4; ++r){
                float v = acc[mt][nt][r] + bia;
                size_t idx = (size_t)(row + r)*ldc + col;
                if constexpr (sizeof(OUT_T) == 2) ((bf16*)C)[idx] = f2bf(v);
                else                              ((float*)C)[idx] = v;
            }
        }
    }
}

// ---------------- 256-tile 4-phase counted-vmcnt bf16 GEMM ----------------
// BM=BN=256, BK=64, 512 thr = 8 waves (2M x 4N), per-wave C = 128x64
// (acc[8][4]). LDS 128 KiB: 2 bufs x {A half0, A half1, B half0, B half1}
// x 16 KiB (half = 128 rows x 64 k). Staging: global_load_lds w=16, LINEAR
// LDS dest, PRE-SWIZZLED global source col (c^ (row&7)); ds_read applies the
// same XOR -> conflict-free b128 frag reads (rule-21 involution pair).
// Counted pipeline: all 8 next-tile loads issued at tile start, then
// s_waitcnt vmcnt(8) (never 0 in-loop) + raw s_barrier. 4 phases x 16 MFMA
// with frag reuse (24 ds_read_b128 / tile), setprio around MFMA clusters.
template<typename OUT_T>
__global__ __launch_bounds__(512, 2) void gemm256(const bf16* __restrict__ A, int lda,
                                                  const bf16* __restrict__ Bt, int ldb,
                                                  const float* __restrict__ bias,
                                                  OUT_T* __restrict__ C, int ldc, int Kdim){
    __shared__ __align__(16) char lds[131072];
    const int tid  = threadIdx.x;
    const int lane = tid & 63;
    const int w    = tid >> 6;            // 0..7
    const int wm   = w >> 2, wn = w & 3;  // 2 x 4
    const int quad = lane >> 4, l15 = lane & 15;
    const int sw   = l15 & 7;
    const int bn0  = blockIdx.x * 256, bm0 = blockIdx.y * 256;

    // staging granules: g covers one half-tile (128 rows x 64 k) as 1024 x 16B
    const int g1 = tid, g2 = tid + 512;
    const int r1 = g1 >> 3, c1 = g1 & 7;
    const int r2 = g2 >> 3, c2 = g2 & 7;
    const int d1 = g1 * 16, d2 = g2 * 16;           // LDS byte offset in half
    // pre-swizzled global source column: element col = ((c ^ (r&7)) * 8)
    const char* pA0g1 = (const char*)(A  + (size_t)(bm0 +       r1)*lda + ((c1 ^ (r1 & 7)) << 3));
    const char* pA0g2 = (const char*)(A  + (size_t)(bm0 +       r2)*lda + ((c2 ^ (r2 & 7)) << 3));
    const char* pA1g1 = (const char*)(A  + (size_t)(bm0 + 128 + r1)*lda + ((c1 ^ (r1 & 7)) << 3));
    const char* pA1g2 = (const char*)(A  + (size_t)(bm0 + 128 + r2)*lda + ((c2 ^ (r2 & 7)) << 3));
    const char* pB0g1 = (const char*)(Bt + (size_t)(bn0 +       r1)*ldb + ((c1 ^ (r1 & 7)) << 3));
    const char* pB0g2 = (const char*)(Bt + (size_t)(bn0 +       r2)*ldb + ((c2 ^ (r2 & 7)) << 3));
    const char* pB1g1 = (const char*)(Bt + (size_t)(bn0 + 128 + r1)*ldb + ((c1 ^ (r1 & 7)) << 3));
    const char* pB1g2 = (const char*)(Bt + (size_t)(bn0 + 128 + r2)*ldb + ((c2 ^ (r2 & 7)) << 3));

    auto STAGE = [&](int bufb, int kby){
        cp16_g2l(pA0g1 + kby, lds + bufb +         d1);
        cp16_g2l(pA0g2 + kby, lds + bufb +         d2);
        cp16_g2l(pA1g1 + kby, lds + bufb + 16384 + d1);
        cp16_g2l(pA1g2 + kby, lds + bufb + 16384 + d2);
        cp16_g2l(pB0g1 + kby, lds + bufb + 32768 + d1);
        cp16_g2l(pB0g2 + kby, lds + bufb + 32768 + d2);
        cp16_g2l(pB1g1 + kby, lds + bufb + 49152 + d1);
        cp16_g2l(pB1g2 + kby, lds + bufb + 49152 + d2);
    };

    // frag-read bases: wave wm reads A half wm; wave wn reads B half (wn>>1),
    // local row base (wn&1)*64. Swizzle: 16B slot (kk*4+quad) ^ sw.
    const int abase = (wm ? 16384 : 0);
    const int bbase = 32768 + ((wn >> 1) ? 16384 : 0);
    const int brow0 = (wn & 1) * 64;
    auto LDA = [&](int bufb, int mt, int kk) -> short8 {
        return *(const short8*)(lds + bufb + abase + (mt*16 + l15)*128
                                + (((kk*4 + quad) ^ sw) << 4));
    };
    auto LDB = [&](int bufb, int nt, int kk) -> short8 {
        return *(const short8*)(lds + bufb + bbase + (brow0 + nt*16 + l15)*128
                                + (((kk*4 + quad) ^ sw) << 4));
    };

    float4_ acc[8][4] = {};
    const int NT = Kdim >> 6;

    STAGE(0, 0);
    asm volatile("s_waitcnt vmcnt(0)" ::: "memory");
    __builtin_amdgcn_s_barrier();

    int cur = 0;
    for (int kt = 0; kt < NT; ++kt){
        const int bufb = cur << 16;
        if (kt + 1 < NT){
            STAGE(bufb ^ 65536, (kt + 1) << 7);          // 8 loads for next tile
            asm volatile("s_waitcnt vmcnt(8)" ::: "memory");  // this tile arrived
        } else {
            asm volatile("s_waitcnt vmcnt(0)" ::: "memory");
        }
        __builtin_amdgcn_s_barrier();

        short8 af[4][2], bf[2][2], bg[2][2];
        // ---- P0: A mt0-3 + B nt0-1 -> acc[0..3][0..1] ----
        #pragma unroll
        for (int mt = 0; mt < 4; ++mt){ af[mt][0] = LDA(bufb, mt, 0); af[mt][1] = LDA(bufb, mt, 1); }
        #pragma unroll
        for (int nt = 0; nt < 2; ++nt){ bf[nt][0] = LDB(bufb, nt, 0); bf[nt][1] = LDB(bufb, nt, 1); }
        __builtin_amdgcn_s_setprio(1);
        #pragma unroll
        for (int mt = 0; mt < 4; ++mt)
            #pragma unroll
            for (int nt = 0; nt < 2; ++nt){
                acc[mt][nt] = MFMA16(af[mt][0], bf[nt][0], acc[mt][nt], 0, 0, 0);
                acc[mt][nt] = MFMA16(af[mt][1], bf[nt][1], acc[mt][nt], 0, 0, 0);
            }
        __builtin_amdgcn_s_setprio(0);
        __builtin_amdgcn_s_barrier();
        // ---- P1: B nt2-3 -> acc[0..3][2..3] (A reused) ----
        #pragma unroll
        for (int nt = 0; nt < 2; ++nt){ bg[nt][0] = LDB(bufb, nt + 2, 0); bg[nt][1] = LDB(bufb, nt + 2, 1); }
        __builtin_amdgcn_s_setprio(1);
        #pragma unroll
        for (int mt = 0; mt < 4; ++mt)
            #pragma unroll
            for (int nt = 0; nt < 2; ++nt){
                acc[mt][nt+2] = MFMA16(af[mt][0], bg[nt][0], acc[mt][nt+2], 0, 0, 0);
                acc[mt][nt+2] = MFMA16(af[mt][1], bg[nt][1], acc[mt][nt+2], 0, 0, 0);
            }
        __builtin_amdgcn_s_setprio(0);
        __builtin_amdgcn_s_barrier();
        // ---- P2: A mt4-7 -> acc[4..7][2..3] (B nt2-3 reused) ----
        #pragma unroll
        for (int mt = 0; mt < 4; ++mt){ af[mt][0] = LDA(bufb, mt + 4, 0); af[mt][1] = LDA(bufb, mt + 4, 1); }
        __builtin_amdgcn_s_setprio(1);
        #pragma unroll
        for (int mt = 0; mt < 4; ++mt)
            #pragma unroll
            for (int nt = 0; nt < 2; ++nt){
                acc[mt+4][nt+2] = MFMA16(af[mt][0], bg[nt][0], acc[mt+4][nt+2], 0, 0, 0);
                acc[mt+4][nt+2] = MFMA16(af[mt][1], bg[nt][1], acc[mt+4][nt+2], 0, 0, 0);
            }
        __builtin_amdgcn_s_setprio(0);
        __builtin_amdgcn_s_barrier();
        // ---- P3: acc[4..7][0..1] (A mt4-7 and B nt0-1 reused, 0 reads) ----
        __builtin_amdgcn_s_setprio(1);
        #pragma unroll
        for (int mt = 0; mt < 4; ++mt)
            #pragma unroll
            for (int nt = 0; nt < 2; ++nt){
                acc[mt+4][nt] = MFMA16(af[mt][0], bf[nt][0], acc[mt+4][nt], 0, 0, 0);
                acc[mt+4][nt] = MFMA16(af[mt][1], bf[nt][1], acc[mt+4][nt], 0, 0, 0);
            }
        __builtin_amdgcn_s_setprio(0);
        __builtin_amdgcn_s_barrier();   // end of tile: all reads of buf done
        cur ^= 1;
    }

    // epilogue: C/D layout col=lane&15, row=quad*4+reg
    #pragma unroll
    for (int mt = 0; mt < 8; ++mt){
        int row = bm0 + wm*128 + mt*16 + quad*4;
        #pragma unroll
        for (int nt = 0; nt < 4; ++nt){
            int col = bn0 + wn*64 + nt*16 + l15;
            float bia = bias[col];
            #pragma unroll
            for (int r = 0; r < 4; ++r){
                float v = acc[mt][nt][r] + bia;
                size_t idx = (size_t)(row + r)*ldc + col;
                if constexpr (sizeof(OUT_T) == 2) ((bf16*)C)[idx] = f2bf(v);
                else                              ((float*)C)[idx] = v;
            }
        }
    }
}

// ---------------- RoPE apply in-place on q,k inside qkv (inline trig) --------
__global__ void rope_apply(bf16* __restrict__ qkv){
    int idx = blockIdx.x * blockDim.x + threadIdx.x;  // ((b*S+s)*H + h)*64 + p
    int p = idx & 63;
    int h = (idx >> 6) & (H_-1);
    int s = (idx >> 10) & (S_-1);
    int b = idx >> 21;
    float freq = powf(10000.0f, -(float)(2*p) / (float)HD_);
    float ang = (float)s * freq;
    float c = cosf(ang), sn = sinf(ang);
    size_t base = (size_t)(b*S_ + s) * N3_ + h*HD_ + 2*p;
    float tr = bf2f(qkv[base]), ti = bf2f(qkv[base+1]);
    qkv[base]   = f2bf(tr*c - ti*sn);
    qkv[base+1] = f2bf(tr*sn + ti*c);
    size_t kb = base + D_;
    tr = bf2f(qkv[kb]); ti = bf2f(qkv[kb+1]);
    qkv[kb]   = f2bf(tr*c - ti*sn);
    qkv[kb+1] = f2bf(tr*sn + ti*c);
}

// prefetch register set: by-value struct (SROA-friendly)
struct KV { short8 k0, k1, v0, v1; };

// ---------------- causal flash attention (round-7 kernel, unchanged) --------
__global__ __launch_bounds__(512, 2) void attn(bf16* __restrict__ QKV){
    const int bid  = blockIdx.x;
    const int xcd  = bid & 7, slot = bid >> 3;
    const int bh   = xcd*8 + (slot & 7);
    const int tp   = slot >> 3;                 // 0..7
    const int b = bh >> 4, h = bh & 15;
    const int tid = threadIdx.x;
    const int w = tid >> 6, lane = tid & 63, quad = lane >> 4, l15 = lane & 15;
    bf16* Qp = QKV + (size_t)b*S_*N3_ + h*HD_;
    const bf16* Kp = Qp + D_;
    const bf16* Vp = Qp + 2*D_;
    __shared__ __align__(16) bf16 Ks[64*128];      // [key][d], XOR swizzled
    __shared__ __align__(16) bf16 Vt[128*64];      // [d][key], XOR swizzled
    __shared__ __align__(16) bf16 Pls[8*16*64];    // per-wave [16][64], XOR swz

    const int skey = tid >> 3;           // 0..63
    const int st   = tid & 7;            // 32B col group
    const int kswz = (skey & 7) << 4;

    const float scale2 = 0.12751707470412558f;  // (1/sqrt(128)) * log2(e)

    auto load_kv = [&](int kb) -> KV {
        KV r;
        const char* krow = (const char*)&Kp[(size_t)(kb + skey)*N3_];
        const char* vrow = (const char*)&Vp[(size_t)(kb + skey)*N3_];
        r.k0 = *(const short8*)(krow + st*32);
        r.k1 = *(const short8*)(krow + st*32 + 16);
        r.v0 = *(const short8*)(vrow + st*32);
        r.v1 = *(const short8*)(vrow + st*32 + 16);
        return r;
    };
    auto stage_write = [&](KV x){
        *(short8*)((char*)Ks + ((skey*256 + st*32     ) ^ kswz)) = x.k0;
        *(short8*)((char*)Ks + ((skey*256 + st*32 + 16) ^ kswz)) = x.k1;
        #pragma unroll
        for (int g = 0; g < 2; ++g){
            short8 vv = g ? x.v1 : x.v0;
            #pragma unroll
            for (int j = 0; j < 8; ++j){
                const int d = st*16 + g*8 + j;   // d&7==j, d>>5==st>>1
                *(short*)((char*)Vt + ((d*128 + skey*2)
                          ^ (((j ^ (st >> 1)) & 7) << 4))) = vv[j];
            }
        }
    };

    KV a = load_kv(0);                   // prologue: chunk 0 of half 0
    KV bset;

    for (int half = 0; half < 2; ++half){
        const int t = half ? (15 - tp) : tp;
        const int qrow = t*128 + w*16 + l15;
        short8 qf[4];
        #pragma unroll
        for (int kc = 0; kc < 4; ++kc)
            qf[kc] = *(const short8*)&Qp[(size_t)qrow*N3_ + kc*32 + quad*8];

        float4_ accO[8] = {};
        float m_i[4], l_i[4];
        #pragma unroll
        for (int r = 0; r < 4; ++r){ m_i[r] = -3.0e38f; l_i[r] = 0.0f; }
        const int rbase = t*128 + w*16 + quad*4;
        const int wmax  = t*128 + w*16 + 15;
        const int nch = 2*t + 2;         // always even
        const int nch1 = 32 - 2*tp;      // half-1 chunk count (for transition)
        auto kb_of = [&](int s){ return (half ? (nch - 1 - s) : s) * 64; };

        auto compute = [&](int kb){
            float4_ sacc[4] = {};
            __builtin_amdgcn_s_setprio(1);
            #pragma unroll
            for (int kc = 0; kc < 4; ++kc)
                #pragma unroll
                for (int nt = 0; nt < 4; ++nt){
                    short8 kf = *(const short8*)((const char*)Ks +
                        (((nt*16 + l15)*256 + kc*64 + quad*16) ^ ((l15 & 7) << 4)));
                    sacc[nt] = MFMA16(qf[kc], kf, sacc[nt], 0, 0, 0);
                }
            __builtin_amdgcn_s_setprio(0);

            #pragma unroll
            for (int nt = 0; nt < 4; ++nt){
                const int j = kb + nt*16 + l15;
                #pragma unroll
                for (int r = 0; r < 4; ++r){
                    float v = sacc[nt][r] * scale2;
                    sacc[nt][r] = (j > rbase + r) ? -3.0e38f : v;
                }
            }

            float alpha[4];
            #pragma unroll
            for (int r = 0; r < 4; ++r){
                float v = fmaxf(fmaxf(sacc[0][r], sacc[1][r]), fmaxf(sacc[2][r], sacc[3][r]));
                v = fmaxf(v, m_i[r]);
                #pragma unroll
                for (int off = 1; off < 16; off <<= 1) v = fmaxf(v, __shfl_xor(v, off, 64));
                alpha[r] = exp2f(m_i[r] - v);
                m_i[r] = v;
                float s = 0.0f;
                #pragma unroll
                for (int nt = 0; nt < 4; ++nt){
                    float p = exp2f(sacc[nt][r] - v);
                    sacc[nt][r] = p; s += p;
                }
                #pragma unroll
                for (int off = 1; off < 16; off <<= 1) s += __shfl_xor(s, off, 64);
                l_i[r] = l_i[r]*alpha[r] + s;
            }
            #pragma unroll
            for (int dt = 0; dt < 8; ++dt)
                #pragma unroll
                for (int r = 0; r < 4; ++r) accO[dt][r] *= alpha[r];

            #pragma unroll
            for (int nt = 0; nt < 4; ++nt)
                #pragma unroll
                for (int r = 0; r < 4; ++r){
                    const int prow = quad*4 + r;
                    *(short*)((char*)Pls + ((w*2048 + prow*128 + (nt*16 + l15)*2)
                                            ^ ((prow & 7) << 4))) = f2bfs(sacc[nt][r]);
                }
            __asm volatile("s_waitcnt lgkmcnt(0)" ::: "memory");
            short8 pf0 = *(const short8*)((const char*)Pls +
                ((w*2048 + l15*128      + quad*16) ^ ((l15 & 7) << 4)));
            short8 pf1 = *(const short8*)((const char*)Pls +
                ((w*2048 + l15*128 + 64 + quad*16) ^ ((l15 & 7) << 4)));

            __builtin_amdgcn_s_setprio(1);
            #pragma unroll
            for (int dt = 0; dt < 8; ++dt){
                const int rb = (dt*16 + l15)*128;
                const int sw2 = (((l15 & 7) ^ (dt >> 1)) & 7) << 4;
                short8 vf0 = *(const short8*)((const char*)Vt + ((rb      + quad*16) ^ sw2));
                short8 vf1 = *(const short8*)((const char*)Vt + ((rb + 64 + quad*16) ^ sw2));
                accO[dt] = MFMA16(pf0, vf0, accO[dt], 0, 0, 0);
                accO[dt] = MFMA16(pf1, vf1, accO[dt], 0, 0, 0);
            }
            __builtin_amdgcn_s_setprio(0);
        };

        for (int s = 0; s < nch; s += 2){
            __syncthreads();               // WAR: prev chunk's LDS reads done
            stage_write(a);
            bset = load_kv(kb_of(s + 1));  // rides under this chunk's compute
            __syncthreads();
            { const int kb0 = kb_of(s); if (kb0 <= wmax) compute(kb0); }

            __syncthreads();
            stage_write(bset);
            if (s + 2 < nch)      a = load_kv(kb_of(s + 2));
            else if (half == 0)   a = load_kv((nch1 - 1) * 64);  // half1 starts high
            __syncthreads();
            { const int kb1 = kb_of(s + 1); if (kb1 <= wmax) compute(kb1); }
        }

        float inv[4];
        #pragma unroll
        for (int r = 0; r < 4; ++r) inv[r] = 1.0f / l_i[r];
        #pragma unroll
        for (int dt = 0; dt < 8; ++dt)
            #pragma unroll
            for (int r = 0; r < 4; ++r){
                int s = t*128 + w*16 + quad*4 + r;
                int d = dt*16 + l15;
                Qp[(size_t)s*N3_ + d] = f2bf(accO[dt][r]*inv[r]);
            }
    }
}

// ---------------- launch ----------------
extern "C" void kernel_launch(void* const* d_in, const int* in_sizes, int n_in,
                              void* d_out, int out_size, void* d_ws, size_t ws_size,
                              hipStream_t stream){
    const float* x    = (const float*)d_in[0];
    const float* Wqkv = (const float*)d_in[1];
    const float* bqkv = (const float*)d_in[2];
    const float* Wo   = (const float*)d_in[3];
    const float* bo   = (const float*)d_in[4];
    float* out = (float*)d_out;
    char* ws = (char*)d_ws;

    // qkv is the only mandatory buffer: 8192 x 6144 bf16 = 100,663,296 B (96 MiB)
    bf16* qkv = (bf16*)(ws + 0);

    // Fast path needs additionally: xb 32 MiB + wqkvb 24 MiB + wob 8 MiB -> 160 MiB total
    const size_t OFF_XB = 100663296, OFF_WQ = 134217728, OFF_WO = 159383552;
    const bool big = (ws_size >= (size_t)167772160);

    if (big){
        bf16* xb    = (bf16*)(ws + OFF_XB);
        bf16* wqkvb = (bf16*)(ws + OFF_WQ);
        bf16* wob   = (bf16*)(ws + OFF_WO);
        long n8;
        n8 = (long)M_*D_/8;   cast_f32_bf16<<<(n8+255)/256, 256, 0, stream>>>(x, xb, n8);
        n8 = (long)N3_*D_/8;  cast_f32_bf16<<<(n8+255)/256, 256, 0, stream>>>(Wqkv, wqkvb, n8);
        n8 = (long)D_*D_/8;   cast_f32_bf16<<<(n8+255)/256, 256, 0, stream>>>(Wo, wob, n8);
        gemm256<bf16><<<dim3(N3_/256, M_/256), 512, 0, stream>>>(
            xb, D_, wqkvb, D_, bqkv, qkv, N3_, D_);
        rope_apply<<<(B_*S_*H_*64)/256, 256, 0, stream>>>(qkv);
        attn<<<dim3(512), 512, 0, stream>>>(qkv);
        gemm256<float><<<dim3(D_/256, M_/256), 512, 0, stream>>>(
            qkv, N3_, wob, D_, bo, out, D_, D_);
    } else {
        // compact path: fp32 inputs converted during GEMM staging; 96 MiB workspace
        gemm_bt<float,float,bf16><<<dim3(N3_/128, M_/128), 256, 0, stream>>>(
            x, D_, Wqkv, D_, bqkv, qkv, N3_, D_);
        rope_apply<<<(B_*S_*H_*64)/256, 256, 0, stream>>>(qkv);
        attn<<<dim3(512), 512, 0, stream>>>(qkv);
        gemm_bt<bf16,float,float><<<dim3(D_/128, M_/128), 256, 0, stream>>>(
            qkv, N3_, Wo, D_, bo, out, D_, D_);
    }
}

// Round 9
// 604.479 us; speedup vs baseline: 2.0014x; 1.0784x over previous
//
#include <hip/hip_runtime.h>
#include <hip/hip_bf16.h>
#include <math.h>

// Problem constants
#define B_   4
#define S_   2048
#define D_   2048
#define H_   16
#define HD_  128
#define N3_  6144   // 3*D
#define M_   8192   // B*S

typedef __attribute__((ext_vector_type(8))) short  short8;
typedef __attribute__((ext_vector_type(4))) float  float4_;

using bf16 = __hip_bfloat16;

static __device__ __forceinline__ float bf2f(bf16 v){ return __bfloat162float(v); }
static __device__ __forceinline__ bf16  f2bf(float v){ return __float2bfloat16(v); }
static __device__ __forceinline__ short f2bfs(float v){
    return (short)__builtin_bit_cast(unsigned short, __float2bfloat16(v));
}

// load 8 elements as bf16 short8 — overloaded on source dtype
static __device__ __forceinline__ short8 load8(const bf16* p){ return *(const short8*)p; }
static __device__ __forceinline__ short8 load8(const float* p){
    float4_ a = *(const float4_*)p;
    float4_ b = *(const float4_*)(p + 4);
    short8 r;
    r[0]=f2bfs(a[0]); r[1]=f2bfs(a[1]); r[2]=f2bfs(a[2]); r[3]=f2bfs(a[3]);
    r[4]=f2bfs(b[0]); r[5]=f2bfs(b[1]); r[6]=f2bfs(b[2]); r[7]=f2bfs(b[3]);
    return r;
}

// async global->LDS 16B copy (global_load_lds_dwordx4)
static __device__ __forceinline__ void cp16_g2l(const void* g, void* l){
    __builtin_amdgcn_global_load_lds((const __attribute__((address_space(1))) void*)g,
                                     (__attribute__((address_space(3))) void*)l,
                                     16, 0, 0);
}

#define MFMA16 __builtin_amdgcn_mfma_f32_16x16x32_bf16

// ---------------- cast fp32 -> bf16 (fast path only) ----------------
__global__ void cast_f32_bf16(const float* __restrict__ in, bf16* __restrict__ out, long n8){
    long i = (long)blockIdx.x * blockDim.x + threadIdx.x;
    if (i >= n8) return;
    *((short8*)out + i) = load8(in + 8*i);
}

// ---------------- legacy 128-tile GEMM (compact path only) ----------------
template<typename AT, typename BT, typename OUT_T>
__global__ __launch_bounds__(256) void gemm_bt(const AT* __restrict__ A, int lda,
                                               const BT* __restrict__ Bt, int ldb,
                                               const float* __restrict__ bias,
                                               OUT_T* __restrict__ C, int ldc, int Kdim){
    __shared__ __align__(16) bf16 As[128*32];
    __shared__ __align__(16) bf16 Bs[128*32];
    const int tid  = threadIdx.x;
    const int lane = tid & 63;
    const int w    = tid >> 6;
    const int wm   = w >> 1, wn = w & 1;
    const int quad = lane >> 4, l15 = lane & 15;
    const int bn0  = blockIdx.x * 128, bm0 = blockIdx.y * 128;
    const int srow = tid >> 2;          // 0..63
    const int scol = (tid & 3) * 8;     // 0,8,16,24

    float4_ acc[4][4] = {};

    for (int k0 = 0; k0 < Kdim; k0 += 32){
        __syncthreads();
        #pragma unroll
        for (int half = 0; half < 2; ++half){
            int r = half*64 + srow;
            *(short8*)&As[r*32 + scol] = load8(&A[(size_t)(bm0 + r)*lda + k0 + scol]);
            *(short8*)&Bs[r*32 + scol] = load8(&Bt[(size_t)(bn0 + r)*ldb + k0 + scol]);
        }
        __syncthreads();
        short8 af[4], bfr[4];
        #pragma unroll
        for (int mt = 0; mt < 4; ++mt) af[mt]  = *(const short8*)&As[(wm*64 + mt*16 + l15)*32 + quad*8];
        #pragma unroll
        for (int nt = 0; nt < 4; ++nt) bfr[nt] = *(const short8*)&Bs[(wn*64 + nt*16 + l15)*32 + quad*8];
        #pragma unroll
        for (int mt = 0; mt < 4; ++mt)
            #pragma unroll
            for (int nt = 0; nt < 4; ++nt)
                acc[mt][nt] = MFMA16(af[mt], bfr[nt], acc[mt][nt], 0, 0, 0);
    }

    #pragma unroll
    for (int mt = 0; mt < 4; ++mt){
        int row = bm0 + wm*64 + mt*16 + quad*4;
        #pragma unroll
        for (int nt = 0; nt < 4; ++nt){
            int col = bn0 + wn*64 + nt*16 + l15;
            float bia = bias[col];
            #pragma unroll
            for (int r = 0; r < 4; ++r){
                float v = acc[mt][nt][r] + bia;
                size_t idx = (size_t)(row + r)*ldc + col;
                if constexpr (sizeof(OUT_T) == 2) ((bf16*)C)[idx] = f2bf(v);
                else                              ((float*)C)[idx] = v;
            }
        }
    }
}

// ---------------- 256-tile 4-phase counted-vmcnt bf16 GEMM (round-8) -------
template<typename OUT_T>
__global__ __launch_bounds__(512, 2) void gemm256(const bf16* __restrict__ A, int lda,
                                                  const bf16* __restrict__ Bt, int ldb,
                                                  const float* __restrict__ bias,
                                                  OUT_T* __restrict__ C, int ldc, int Kdim){
    __shared__ __align__(16) char lds[131072];
    const int tid  = threadIdx.x;
    const int lane = tid & 63;
    const int w    = tid >> 6;            // 0..7
    const int wm   = w >> 2, wn = w & 3;  // 2 x 4
    const int quad = lane >> 4, l15 = lane & 15;
    const int sw   = l15 & 7;
    const int bn0  = blockIdx.x * 256, bm0 = blockIdx.y * 256;

    const int g1 = tid, g2 = tid + 512;
    const int r1 = g1 >> 3, c1 = g1 & 7;
    const int r2 = g2 >> 3, c2 = g2 & 7;
    const int d1 = g1 * 16, d2 = g2 * 16;
    const char* pA0g1 = (const char*)(A  + (size_t)(bm0 +       r1)*lda + ((c1 ^ (r1 & 7)) << 3));
    const char* pA0g2 = (const char*)(A  + (size_t)(bm0 +       r2)*lda + ((c2 ^ (r2 & 7)) << 3));
    const char* pA1g1 = (const char*)(A  + (size_t)(bm0 + 128 + r1)*lda + ((c1 ^ (r1 & 7)) << 3));
    const char* pA1g2 = (const char*)(A  + (size_t)(bm0 + 128 + r2)*lda + ((c2 ^ (r2 & 7)) << 3));
    const char* pB0g1 = (const char*)(Bt + (size_t)(bn0 +       r1)*ldb + ((c1 ^ (r1 & 7)) << 3));
    const char* pB0g2 = (const char*)(Bt + (size_t)(bn0 +       r2)*ldb + ((c2 ^ (r2 & 7)) << 3));
    const char* pB1g1 = (const char*)(Bt + (size_t)(bn0 + 128 + r1)*ldb + ((c1 ^ (r1 & 7)) << 3));
    const char* pB1g2 = (const char*)(Bt + (size_t)(bn0 + 128 + r2)*ldb + ((c2 ^ (r2 & 7)) << 3));

    auto STAGE = [&](int bufb, int kby){
        cp16_g2l(pA0g1 + kby, lds + bufb +         d1);
        cp16_g2l(pA0g2 + kby, lds + bufb +         d2);
        cp16_g2l(pA1g1 + kby, lds + bufb + 16384 + d1);
        cp16_g2l(pA1g2 + kby, lds + bufb + 16384 + d2);
        cp16_g2l(pB0g1 + kby, lds + bufb + 32768 + d1);
        cp16_g2l(pB0g2 + kby, lds + bufb + 32768 + d2);
        cp16_g2l(pB1g1 + kby, lds + bufb + 49152 + d1);
        cp16_g2l(pB1g2 + kby, lds + bufb + 49152 + d2);
    };

    const int abase = (wm ? 16384 : 0);
    const int bbase = 32768 + ((wn >> 1) ? 16384 : 0);
    const int brow0 = (wn & 1) * 64;
    auto LDA = [&](int bufb, int mt, int kk) -> short8 {
        return *(const short8*)(lds + bufb + abase + (mt*16 + l15)*128
                                + (((kk*4 + quad) ^ sw) << 4));
    };
    auto LDB = [&](int bufb, int nt, int kk) -> short8 {
        return *(const short8*)(lds + bufb + bbase + (brow0 + nt*16 + l15)*128
                                + (((kk*4 + quad) ^ sw) << 4));
    };

    float4_ acc[8][4] = {};
    const int NT = Kdim >> 6;

    STAGE(0, 0);
    asm volatile("s_waitcnt vmcnt(0)" ::: "memory");
    __builtin_amdgcn_s_barrier();

    int cur = 0;
    for (int kt = 0; kt < NT; ++kt){
        const int bufb = cur << 16;
        if (kt + 1 < NT){
            STAGE(bufb ^ 65536, (kt + 1) << 7);
            asm volatile("s_waitcnt vmcnt(8)" ::: "memory");
        } else {
            asm volatile("s_waitcnt vmcnt(0)" ::: "memory");
        }
        __builtin_amdgcn_s_barrier();

        short8 af[4][2], bf[2][2], bg[2][2];
        #pragma unroll
        for (int mt = 0; mt < 4; ++mt){ af[mt][0] = LDA(bufb, mt, 0); af[mt][1] = LDA(bufb, mt, 1); }
        #pragma unroll
        for (int nt = 0; nt < 2; ++nt){ bf[nt][0] = LDB(bufb, nt, 0); bf[nt][1] = LDB(bufb, nt, 1); }
        __builtin_amdgcn_s_setprio(1);
        #pragma unroll
        for (int mt = 0; mt < 4; ++mt)
            #pragma unroll
            for (int nt = 0; nt < 2; ++nt){
                acc[mt][nt] = MFMA16(af[mt][0], bf[nt][0], acc[mt][nt], 0, 0, 0);
                acc[mt][nt] = MFMA16(af[mt][1], bf[nt][1], acc[mt][nt], 0, 0, 0);
            }
        __builtin_amdgcn_s_setprio(0);
        __builtin_amdgcn_s_barrier();
        #pragma unroll
        for (int nt = 0; nt < 2; ++nt){ bg[nt][0] = LDB(bufb, nt + 2, 0); bg[nt][1] = LDB(bufb, nt + 2, 1); }
        __builtin_amdgcn_s_setprio(1);
        #pragma unroll
        for (int mt = 0; mt < 4; ++mt)
            #pragma unroll
            for (int nt = 0; nt < 2; ++nt){
                acc[mt][nt+2] = MFMA16(af[mt][0], bg[nt][0], acc[mt][nt+2], 0, 0, 0);
                acc[mt][nt+2] = MFMA16(af[mt][1], bg[nt][1], acc[mt][nt+2], 0, 0, 0);
            }
        __builtin_amdgcn_s_setprio(0);
        __builtin_amdgcn_s_barrier();
        #pragma unroll
        for (int mt = 0; mt < 4; ++mt){ af[mt][0] = LDA(bufb, mt + 4, 0); af[mt][1] = LDA(bufb, mt + 4, 1); }
        __builtin_amdgcn_s_setprio(1);
        #pragma unroll
        for (int mt = 0; mt < 4; ++mt)
            #pragma unroll
            for (int nt = 0; nt < 2; ++nt){
                acc[mt+4][nt+2] = MFMA16(af[mt][0], bg[nt][0], acc[mt+4][nt+2], 0, 0, 0);
                acc[mt+4][nt+2] = MFMA16(af[mt][1], bg[nt][1], acc[mt+4][nt+2], 0, 0, 0);
            }
        __builtin_amdgcn_s_setprio(0);
        __builtin_amdgcn_s_barrier();
        __builtin_amdgcn_s_setprio(1);
        #pragma unroll
        for (int mt = 0; mt < 4; ++mt)
            #pragma unroll
            for (int nt = 0; nt < 2; ++nt){
                acc[mt+4][nt] = MFMA16(af[mt][0], bf[nt][0], acc[mt+4][nt], 0, 0, 0);
                acc[mt+4][nt] = MFMA16(af[mt][1], bf[nt][1], acc[mt+4][nt], 0, 0, 0);
            }
        __builtin_amdgcn_s_setprio(0);
        __builtin_amdgcn_s_barrier();
        cur ^= 1;
    }

    #pragma unroll
    for (int mt = 0; mt < 8; ++mt){
        int row = bm0 + wm*128 + mt*16 + quad*4;
        #pragma unroll
        for (int nt = 0; nt < 4; ++nt){
            int col = bn0 + wn*64 + nt*16 + l15;
            float bia = bias[col];
            #pragma unroll
            for (int r = 0; r < 4; ++r){
                float v = acc[mt][nt][r] + bia;
                size_t idx = (size_t)(row + r)*ldc + col;
                if constexpr (sizeof(OUT_T) == 2) ((bf16*)C)[idx] = f2bf(v);
                else                              ((float*)C)[idx] = v;
            }
        }
    }
}

// ---------------- RoPE apply in-place on q,k inside qkv (inline trig) --------
__global__ void rope_apply(bf16* __restrict__ qkv){
    int idx = blockIdx.x * blockDim.x + threadIdx.x;  // ((b*S+s)*H + h)*64 + p
    int p = idx & 63;
    int h = (idx >> 6) & (H_-1);
    int s = (idx >> 10) & (S_-1);
    int b = idx >> 21;
    float freq = powf(10000.0f, -(float)(2*p) / (float)HD_);
    float ang = (float)s * freq;
    float c = cosf(ang), sn = sinf(ang);
    size_t base = (size_t)(b*S_ + s) * N3_ + h*HD_ + 2*p;
    float tr = bf2f(qkv[base]), ti = bf2f(qkv[base+1]);
    qkv[base]   = f2bf(tr*c - ti*sn);
    qkv[base+1] = f2bf(tr*sn + ti*c);
    size_t kb = base + D_;
    tr = bf2f(qkv[kb]); ti = bf2f(qkv[kb+1]);
    qkv[kb]   = f2bf(tr*c - ti*sn);
    qkv[kb+1] = f2bf(tr*sn + ti*c);
}

// prefetch register set: by-value struct (SROA-friendly)
struct KV { short8 k0, k1, v0, v1; };

// ---------------- causal flash attention ----------------
// 8 waves x 16 q-rows = 128-row q-panel; balanced pairs (tp, 15-tp) = 34
// uniform chunks of 64 keys; bh-major XCD remap + descending half-1 for L2.
// NEW this round:
//  * double-buffered Ks/Vt + ONE raw barrier per chunk: lgkmcnt(0)+s_barrier
//    only — vmcnt free-running, so the register prefetch is never drained.
//  * full-spread scatter swizzles: Vt swz(d)=(d&7)^((d>>4)&7); Pls
//    swz(row)=(row&7)^(((row>>3)&1)<<1) — write-side conflict-free.
//  * T13 defer-softmax: per-lane tile max + __all(<=m+8) skips max-reduce,
//    alpha and O-rescale on stable chunks; l_i kept as per-lane partials,
//    reduced once at the end. Causal mask applied only when kb+63 > wmin.
__global__ __launch_bounds__(512, 2) void attn(bf16* __restrict__ QKV){
    const int bid  = blockIdx.x;
    const int xcd  = bid & 7, slot = bid >> 3;
    const int bh   = xcd*8 + (slot & 7);
    const int tp   = slot >> 3;                 // 0..7
    const int b = bh >> 4, h = bh & 15;
    const int tid = threadIdx.x;
    const int w = tid >> 6, lane = tid & 63, quad = lane >> 4, l15 = lane & 15;
    bf16* Qp = QKV + (size_t)b*S_*N3_ + h*HD_;
    const bf16* Kp = Qp + D_;
    const bf16* Vp = Qp + 2*D_;
    __shared__ __align__(16) bf16 Ks[2*64*128];    // [buf][key][d], swz (row&7)
    __shared__ __align__(16) bf16 Vt[2*128*64];    // [buf][d][key], swz (d&7)^(d>>4)
    __shared__ __align__(16) bf16 Pls[8*16*64];    // per-wave [16][64], swz_P

    const int skey = tid >> 3;           // 0..63
    const int st   = tid & 7;            // 32B col group
    const int kswz = (skey & 7) << 4;

    const float scale2 = 0.12751707470412558f;  // (1/sqrt(128)) * log2(e)

    auto load_kv = [&](int kb) -> KV {
        KV r;
        const char* krow = (const char*)&Kp[(size_t)(kb + skey)*N3_];
        const char* vrow = (const char*)&Vp[(size_t)(kb + skey)*N3_];
        r.k0 = *(const short8*)(krow + st*32);
        r.k1 = *(const short8*)(krow + st*32 + 16);
        r.v0 = *(const short8*)(vrow + st*32);
        r.v1 = *(const short8*)(vrow + st*32 + 16);
        return r;
    };
    auto stage_write = [&](int pbuf, KV x){
        char* kd = (char*)Ks + pbuf*16384;
        char* vd = (char*)Vt + pbuf*16384;
        *(short8*)(kd + ((skey*256 + st*32     ) ^ kswz)) = x.k0;
        *(short8*)(kd + ((skey*256 + st*32 + 16) ^ kswz)) = x.k1;
        #pragma unroll
        for (int g = 0; g < 2; ++g){
            short8 vv = g ? x.v1 : x.v0;
            #pragma unroll
            for (int j = 0; j < 8; ++j){
                const int d = st*16 + g*8 + j;   // d&7==j, (d>>4)&7==st
                *(short*)(vd + ((d*128 + skey*2) ^ (((j ^ st) & 7) << 4))) = vv[j];
            }
        }
    };

    int pb = 0;
    KV a = load_kv(0);                   // prologue: chunk 0 of half 0

    for (int half = 0; half < 2; ++half){
        const int t = half ? (15 - tp) : tp;
        const int qrow = t*128 + w*16 + l15;
        short8 qf[4];
        #pragma unroll
        for (int kc = 0; kc < 4; ++kc)
            qf[kc] = *(const short8*)&Qp[(size_t)qrow*N3_ + kc*32 + quad*8];

        float4_ accO[8] = {};
        float m_i[4], l_i[4];
        #pragma unroll
        for (int r = 0; r < 4; ++r){ m_i[r] = -3.0e38f; l_i[r] = 0.0f; }
        const int rbase = t*128 + w*16 + quad*4;
        const int wmin  = t*128 + w*16;
        const int wmax  = wmin + 15;
        const int nch = 2*t + 2;
        const int nch1 = 32 - 2*tp;      // half-1 chunk count (for transition)
        auto kb_of = [&](int s){ return (half ? (nch - 1 - s) : s) * 64; };

        auto compute = [&](int pbuf, int kb){
            const char* kbs = (const char*)Ks + pbuf*16384;
            const char* vbs = (const char*)Vt + pbuf*16384;
            // ---- QK^T ----
            float4_ sacc[4] = {};
            __builtin_amdgcn_s_setprio(1);
            #pragma unroll
            for (int kc = 0; kc < 4; ++kc)
                #pragma unroll
                for (int nt = 0; nt < 4; ++nt){
                    short8 kf = *(const short8*)(kbs +
                        (((nt*16 + l15)*256 + kc*64 + quad*16) ^ ((l15 & 7) << 4)));
                    sacc[nt] = MFMA16(qf[kc], kf, sacc[nt], 0, 0, 0);
                }
            __builtin_amdgcn_s_setprio(0);

            // ---- scale (exp2 domain); causal mask only near the diagonal ----
            if (kb + 63 > wmin){
                #pragma unroll
                for (int nt = 0; nt < 4; ++nt){
                    const int j = kb + nt*16 + l15;
                    #pragma unroll
                    for (int r = 0; r < 4; ++r){
                        float v = sacc[nt][r] * scale2;
                        sacc[nt][r] = (j > rbase + r) ? -3.0e38f : v;
                    }
                }
            } else {
                #pragma unroll
                for (int nt = 0; nt < 4; ++nt)
                    #pragma unroll
                    for (int r = 0; r < 4; ++r) sacc[nt][r] *= scale2;
            }

            // ---- per-lane tile max + defer decision ----
            float tmax[4];
            #pragma unroll
            for (int r = 0; r < 4; ++r)
                tmax[r] = fmaxf(fmaxf(sacc[0][r], sacc[1][r]),
                                fmaxf(sacc[2][r], sacc[3][r]));
            int stable = (tmax[0] <= m_i[0] + 8.0f) & (tmax[1] <= m_i[1] + 8.0f) &
                         (tmax[2] <= m_i[2] + 8.0f) & (tmax[3] <= m_i[3] + 8.0f);
            if (__all(stable)){
                // defer path: keep m, no reduce, no rescale; l per-lane partial
                #pragma unroll
                for (int r = 0; r < 4; ++r){
                    float s = 0.0f;
                    #pragma unroll
                    for (int nt = 0; nt < 4; ++nt){
                        float p = exp2f(sacc[nt][r] - m_i[r]);
                        sacc[nt][r] = p; s += p;
                    }
                    l_i[r] += s;
                }
            } else {
                float alpha[4];
                #pragma unroll
                for (int r = 0; r < 4; ++r){
                    float v = fmaxf(tmax[r], m_i[r]);
                    #pragma unroll
                    for (int off = 1; off < 16; off <<= 1) v = fmaxf(v, __shfl_xor(v, off, 64));
                    alpha[r] = exp2f(m_i[r] - v);
                    m_i[r] = v;
                    float s = 0.0f;
                    #pragma unroll
                    for (int nt = 0; nt < 4; ++nt){
                        float p = exp2f(sacc[nt][r] - v);
                        sacc[nt][r] = p; s += p;
                    }
                    l_i[r] = l_i[r]*alpha[r] + s;
                }
                #pragma unroll
                for (int dt = 0; dt < 8; ++dt)
                    #pragma unroll
                    for (int r = 0; r < 4; ++r) accO[dt][r] *= alpha[r];
            }

            // ---- P: C-layout -> per-wave LDS [16][64] swz_P -> A-layout ----
            #pragma unroll
            for (int nt = 0; nt < 4; ++nt)
                #pragma unroll
                for (int r = 0; r < 4; ++r){
                    const int prow = quad*4 + r;
                    const int swp = ((prow & 7) ^ (((prow >> 3) & 1) << 1)) << 4;
                    *(short*)((char*)Pls + ((w*2048 + prow*128 + (nt*16 + l15)*2)
                                            ^ swp)) = f2bfs(sacc[nt][r]);
                }
            __asm volatile("s_waitcnt lgkmcnt(0)" ::: "memory");
            const int swr = ((l15 & 7) ^ (((l15 >> 3) & 1) << 1)) << 4;
            short8 pf0 = *(const short8*)((const char*)Pls +
                ((w*2048 + l15*128      + quad*16) ^ swr));
            short8 pf1 = *(const short8*)((const char*)Pls +
                ((w*2048 + l15*128 + 64 + quad*16) ^ swr));

            // ---- PV ----
            __builtin_amdgcn_s_setprio(1);
            #pragma unroll
            for (int dt = 0; dt < 8; ++dt){
                const int rb = (dt*16 + l15)*128;
                const int sw2 = (((l15 & 7) ^ dt) & 7) << 4;   // (d&7)^((d>>4)&7)
                short8 vf0 = *(const short8*)(vbs + ((rb      + quad*16) ^ sw2));
                short8 vf1 = *(const short8*)(vbs + ((rb + 64 + quad*16) ^ sw2));
                accO[dt] = MFMA16(pf0, vf0, accO[dt], 0, 0, 0);
                accO[dt] = MFMA16(pf1, vf1, accO[dt], 0, 0, 0);
            }
            __builtin_amdgcn_s_setprio(0);
        };

        for (int s = 0; s < nch; ++s){
            stage_write(pb, a);
            if (s + 1 < nch)      a = load_kv(kb_of(s + 1));
            else if (half == 0)   a = load_kv((nch1 - 1) * 64);  // half1 starts high
            // single barrier: LDS writes drained, vmcnt left in flight
            asm volatile("s_waitcnt lgkmcnt(0)" ::: "memory");
            __builtin_amdgcn_s_barrier();
            { const int kb = kb_of(s); if (kb <= wmax) compute(pb, kb); }
            pb ^= 1;
        }

        // ---- final l reduce (once) + normalize + write O ----
        float inv[4];
        #pragma unroll
        for (int r = 0; r < 4; ++r){
            float s = l_i[r];
            #pragma unroll
            for (int off = 1; off < 16; off <<= 1) s += __shfl_xor(s, off, 64);
            inv[r] = 1.0f / s;
        }
        #pragma unroll
        for (int dt = 0; dt < 8; ++dt)
            #pragma unroll
            for (int r = 0; r < 4; ++r){
                int s = t*128 + w*16 + quad*4 + r;
                int d = dt*16 + l15;
                Qp[(size_t)s*N3_ + d] = f2bf(accO[dt][r]*inv[r]);
            }
    }
}

// ---------------- launch ----------------
extern "C" void kernel_launch(void* const* d_in, const int* in_sizes, int n_in,
                              void* d_out, int out_size, void* d_ws, size_t ws_size,
                              hipStream_t stream){
    const float* x    = (const float*)d_in[0];
    const float* Wqkv = (const float*)d_in[1];
    const float* bqkv = (const float*)d_in[2];
    const float* Wo   = (const float*)d_in[3];
    const float* bo   = (const float*)d_in[4];
    float* out = (float*)d_out;
    char* ws = (char*)d_ws;

    // qkv is the only mandatory buffer: 8192 x 6144 bf16 = 100,663,296 B (96 MiB)
    bf16* qkv = (bf16*)(ws + 0);

    // Fast path needs additionally: xb 32 MiB + wqkvb 24 MiB + wob 8 MiB -> 160 MiB total
    const size_t OFF_XB = 100663296, OFF_WQ = 134217728, OFF_WO = 159383552;
    const bool big = (ws_size >= (size_t)167772160);

    if (big){
        bf16* xb    = (bf16*)(ws + OFF_XB);
        bf16* wqkvb = (bf16*)(ws + OFF_WQ);
        bf16* wob   = (bf16*)(ws + OFF_WO);
        long n8;
        n8 = (long)M_*D_/8;   cast_f32_bf16<<<(n8+255)/256, 256, 0, stream>>>(x, xb, n8);
        n8 = (long)N3_*D_/8;  cast_f32_bf16<<<(n8+255)/256, 256, 0, stream>>>(Wqkv, wqkvb, n8);
        n8 = (long)D_*D_/8;   cast_f32_bf16<<<(n8+255)/256, 256, 0, stream>>>(Wo, wob, n8);
        gemm256<bf16><<<dim3(N3_/256, M_/256), 512, 0, stream>>>(
            xb, D_, wqkvb, D_, bqkv, qkv, N3_, D_);
        rope_apply<<<(B_*S_*H_*64)/256, 256, 0, stream>>>(qkv);
        attn<<<dim3(512), 512, 0, stream>>>(qkv);
        gemm256<float><<<dim3(D_/256, M_/256), 512, 0, stream>>>(
            qkv, N3_, wob, D_, bo, out, D_, D_);
    } else {
        // compact path: fp32 inputs converted during GEMM staging; 96 MiB workspace
        gemm_bt<float,float,bf16><<<dim3(N3_/128, M_/128), 256, 0, stream>>>(
            x, D_, Wqkv, D_, bqkv, qkv, N3_, D_);
        rope_apply<<<(B_*S_*H_*64)/256, 256, 0, stream>>>(qkv);
        attn<<<dim3(512), 512, 0, stream>>>(qkv);
        gemm_bt<bf16,float,float><<<dim3(D_/128, M_/128), 256, 0, stream>>>(
            qkv, N3_, Wo, D_, bo, out, D_, D_);
    }
}

// Round 10
// 591.502 us; speedup vs baseline: 2.0453x; 1.0219x over previous
//
#include <hip/hip_runtime.h>
#include <hip/hip_bf16.h>
#include <math.h>

// Problem constants
#define B_   4
#define S_   2048
#define D_   2048
#define H_   16
#define HD_  128
#define N3_  6144   // 3*D
#define M_   8192   // B*S

typedef __attribute__((ext_vector_type(8))) short  short8;
typedef __attribute__((ext_vector_type(4))) float  float4_;

using bf16 = __hip_bfloat16;

static __device__ __forceinline__ float bf2f(bf16 v){ return __bfloat162float(v); }
static __device__ __forceinline__ bf16  f2bf(float v){ return __float2bfloat16(v); }
static __device__ __forceinline__ short f2bfs(float v){
    return (short)__builtin_bit_cast(unsigned short, __float2bfloat16(v));
}
static __device__ __forceinline__ float s2f(short v){
    return __bfloat162float(__builtin_bit_cast(bf16, (unsigned short)v));
}

// load 8 elements as bf16 short8 — overloaded on source dtype
static __device__ __forceinline__ short8 load8(const bf16* p){ return *(const short8*)p; }
static __device__ __forceinline__ short8 load8(const float* p){
    float4_ a = *(const float4_*)p;
    float4_ b = *(const float4_*)(p + 4);
    short8 r;
    r[0]=f2bfs(a[0]); r[1]=f2bfs(a[1]); r[2]=f2bfs(a[2]); r[3]=f2bfs(a[3]);
    r[4]=f2bfs(b[0]); r[5]=f2bfs(b[1]); r[6]=f2bfs(b[2]); r[7]=f2bfs(b[3]);
    return r;
}

// async global->LDS 16B copy (global_load_lds_dwordx4)
static __device__ __forceinline__ void cp16_g2l(const void* g, void* l){
    __builtin_amdgcn_global_load_lds((const __attribute__((address_space(1))) void*)g,
                                     (__attribute__((address_space(3))) void*)l,
                                     16, 0, 0);
}

#define MFMA16 __builtin_amdgcn_mfma_f32_16x16x32_bf16

// ---------------- cast fp32 -> bf16 (fast path only) ----------------
__global__ void cast_f32_bf16(const float* __restrict__ in, bf16* __restrict__ out, long n8){
    long i = (long)blockIdx.x * blockDim.x + threadIdx.x;
    if (i >= n8) return;
    *((short8*)out + i) = load8(in + 8*i);
}

// ---------------- legacy 128-tile GEMM (compact path only) ----------------
template<typename AT, typename BT, typename OUT_T>
__global__ __launch_bounds__(256) void gemm_bt(const AT* __restrict__ A, int lda,
                                               const BT* __restrict__ Bt, int ldb,
                                               const float* __restrict__ bias,
                                               OUT_T* __restrict__ C, int ldc, int Kdim){
    __shared__ __align__(16) bf16 As[128*32];
    __shared__ __align__(16) bf16 Bs[128*32];
    const int tid  = threadIdx.x;
    const int lane = tid & 63;
    const int w    = tid >> 6;
    const int wm   = w >> 1, wn = w & 1;
    const int quad = lane >> 4, l15 = lane & 15;
    const int bn0  = blockIdx.x * 128, bm0 = blockIdx.y * 128;
    const int srow = tid >> 2;          // 0..63
    const int scol = (tid & 3) * 8;     // 0,8,16,24

    float4_ acc[4][4] = {};

    for (int k0 = 0; k0 < Kdim; k0 += 32){
        __syncthreads();
        #pragma unroll
        for (int half = 0; half < 2; ++half){
            int r = half*64 + srow;
            *(short8*)&As[r*32 + scol] = load8(&A[(size_t)(bm0 + r)*lda + k0 + scol]);
            *(short8*)&Bs[r*32 + scol] = load8(&Bt[(size_t)(bn0 + r)*ldb + k0 + scol]);
        }
        __syncthreads();
        short8 af[4], bfr[4];
        #pragma unroll
        for (int mt = 0; mt < 4; ++mt) af[mt]  = *(const short8*)&As[(wm*64 + mt*16 + l15)*32 + quad*8];
        #pragma unroll
        for (int nt = 0; nt < 4; ++nt) bfr[nt] = *(const short8*)&Bs[(wn*64 + nt*16 + l15)*32 + quad*8];
        #pragma unroll
        for (int mt = 0; mt < 4; ++mt)
            #pragma unroll
            for (int nt = 0; nt < 4; ++nt)
                acc[mt][nt] = MFMA16(af[mt], bfr[nt], acc[mt][nt], 0, 0, 0);
    }

    #pragma unroll
    for (int mt = 0; mt < 4; ++mt){
        int row = bm0 + wm*64 + mt*16 + quad*4;
        #pragma unroll
        for (int nt = 0; nt < 4; ++nt){
            int col = bn0 + wn*64 + nt*16 + l15;
            float bia = bias[col];
            #pragma unroll
            for (int r = 0; r < 4; ++r){
                float v = acc[mt][nt][r] + bia;
                size_t idx = (size_t)(row + r)*ldc + col;
                if constexpr (sizeof(OUT_T) == 2) ((bf16*)C)[idx] = f2bf(v);
                else                              ((float*)C)[idx] = v;
            }
        }
    }
}

// ---------------- 256-tile counted-vmcnt bf16 GEMM, m201-style windows -----
// BM=BN=256, BK=64, 512 thr = 8 waves (2M x 4N), acc[8][4] (128x64/wave).
// LDS 128 KiB double-buffered. Staging: global_load_lds w=16, linear dest,
// pre-swizzled global source; ds_read applies same XOR (conflicts = 0,
// verified round 9). Counted wait: vmcnt(8) once per tile (never 0 in loop).
// NEW: per-phase double-barrier windows (m201): {reads | barrier |
// lgkmcnt(0)+sched_barrier | setprio MFMA | barrier} so the 8 waves alternate
// clean mem/MFMA windows.
template<typename OUT_T>
__global__ __launch_bounds__(512, 2) void gemm256(const bf16* __restrict__ A, int lda,
                                                  const bf16* __restrict__ Bt, int ldb,
                                                  const float* __restrict__ bias,
                                                  OUT_T* __restrict__ C, int ldc, int Kdim){
    __shared__ __align__(16) char lds[131072];
    const int tid  = threadIdx.x;
    const int lane = tid & 63;
    const int w    = tid >> 6;            // 0..7
    const int wm   = w >> 2, wn = w & 3;  // 2 x 4
    const int quad = lane >> 4, l15 = lane & 15;
    const int sw   = l15 & 7;
    const int bn0  = blockIdx.x * 256, bm0 = blockIdx.y * 256;

    const int g1 = tid, g2 = tid + 512;
    const int r1 = g1 >> 3, c1 = g1 & 7;
    const int r2 = g2 >> 3, c2 = g2 & 7;
    const int d1 = g1 * 16, d2 = g2 * 16;
    const char* pA0g1 = (const char*)(A  + (size_t)(bm0 +       r1)*lda + ((c1 ^ (r1 & 7)) << 3));
    const char* pA0g2 = (const char*)(A  + (size_t)(bm0 +       r2)*lda + ((c2 ^ (r2 & 7)) << 3));
    const char* pA1g1 = (const char*)(A  + (size_t)(bm0 + 128 + r1)*lda + ((c1 ^ (r1 & 7)) << 3));
    const char* pA1g2 = (const char*)(A  + (size_t)(bm0 + 128 + r2)*lda + ((c2 ^ (r2 & 7)) << 3));
    const char* pB0g1 = (const char*)(Bt + (size_t)(bn0 +       r1)*ldb + ((c1 ^ (r1 & 7)) << 3));
    const char* pB0g2 = (const char*)(Bt + (size_t)(bn0 +       r2)*ldb + ((c2 ^ (r2 & 7)) << 3));
    const char* pB1g1 = (const char*)(Bt + (size_t)(bn0 + 128 + r1)*ldb + ((c1 ^ (r1 & 7)) << 3));
    const char* pB1g2 = (const char*)(Bt + (size_t)(bn0 + 128 + r2)*ldb + ((c2 ^ (r2 & 7)) << 3));

    auto STAGE = [&](int bufb, int kby){
        cp16_g2l(pA0g1 + kby, lds + bufb +         d1);
        cp16_g2l(pA0g2 + kby, lds + bufb +         d2);
        cp16_g2l(pA1g1 + kby, lds + bufb + 16384 + d1);
        cp16_g2l(pA1g2 + kby, lds + bufb + 16384 + d2);
        cp16_g2l(pB0g1 + kby, lds + bufb + 32768 + d1);
        cp16_g2l(pB0g2 + kby, lds + bufb + 32768 + d2);
        cp16_g2l(pB1g1 + kby, lds + bufb + 49152 + d1);
        cp16_g2l(pB1g2 + kby, lds + bufb + 49152 + d2);
    };

    const int abase = (wm ? 16384 : 0);
    const int bbase = 32768 + ((wn >> 1) ? 16384 : 0);
    const int brow0 = (wn & 1) * 64;
    auto LDA = [&](int bufb, int mt, int kk) -> short8 {
        return *(const short8*)(lds + bufb + abase + (mt*16 + l15)*128
                                + (((kk*4 + quad) ^ sw) << 4));
    };
    auto LDB = [&](int bufb, int nt, int kk) -> short8 {
        return *(const short8*)(lds + bufb + bbase + (brow0 + nt*16 + l15)*128
                                + (((kk*4 + quad) ^ sw) << 4));
    };

    float4_ acc[8][4] = {};
    const int NT = Kdim >> 6;

    STAGE(0, 0);
    asm volatile("s_waitcnt vmcnt(0)" ::: "memory");
    __builtin_amdgcn_s_barrier();

    int cur = 0;
    for (int kt = 0; kt < NT; ++kt){
        const int bufb = cur << 16;
        // ---- stage next tile + counted wait (once per tile) ----
        if (kt + 1 < NT){
            STAGE(bufb ^ 65536, (kt + 1) << 7);
            asm volatile("s_waitcnt vmcnt(8)" ::: "memory");
        } else {
            asm volatile("s_waitcnt vmcnt(0)" ::: "memory");
        }
        __builtin_amdgcn_s_barrier();

        short8 af[4][2], bf[2][2], bg[2][2];
        // ---- P0: read af(mt0-3) + bf(nt0-1) | bar | MFMA -> acc[0..3][0..1] ----
        #pragma unroll
        for (int mt = 0; mt < 4; ++mt){ af[mt][0] = LDA(bufb, mt, 0); af[mt][1] = LDA(bufb, mt, 1); }
        #pragma unroll
        for (int nt = 0; nt < 2; ++nt){ bf[nt][0] = LDB(bufb, nt, 0); bf[nt][1] = LDB(bufb, nt, 1); }
        __builtin_amdgcn_s_barrier();
        asm volatile("s_waitcnt lgkmcnt(0)" ::: "memory");
        __builtin_amdgcn_sched_barrier(0);
        __builtin_amdgcn_s_setprio(1);
        #pragma unroll
        for (int mt = 0; mt < 4; ++mt)
            #pragma unroll
            for (int nt = 0; nt < 2; ++nt){
                acc[mt][nt] = MFMA16(af[mt][0], bf[nt][0], acc[mt][nt], 0, 0, 0);
                acc[mt][nt] = MFMA16(af[mt][1], bf[nt][1], acc[mt][nt], 0, 0, 0);
            }
        __builtin_amdgcn_s_setprio(0);
        __builtin_amdgcn_s_barrier();
        // ---- P1: read bg(nt2-3) | bar | MFMA -> acc[0..3][2..3] ----
        #pragma unroll
        for (int nt = 0; nt < 2; ++nt){ bg[nt][0] = LDB(bufb, nt + 2, 0); bg[nt][1] = LDB(bufb, nt + 2, 1); }
        __builtin_amdgcn_s_barrier();
        asm volatile("s_waitcnt lgkmcnt(0)" ::: "memory");
        __builtin_amdgcn_sched_barrier(0);
        __builtin_amdgcn_s_setprio(1);
        #pragma unroll
        for (int mt = 0; mt < 4; ++mt)
            #pragma unroll
            for (int nt = 0; nt < 2; ++nt){
                acc[mt][nt+2] = MFMA16(af[mt][0], bg[nt][0], acc[mt][nt+2], 0, 0, 0);
                acc[mt][nt+2] = MFMA16(af[mt][1], bg[nt][1], acc[mt][nt+2], 0, 0, 0);
            }
        __builtin_amdgcn_s_setprio(0);
        __builtin_amdgcn_s_barrier();
        // ---- P2: read af(mt4-7) | bar | MFMA -> acc[4..7][2..3] ----
        #pragma unroll
        for (int mt = 0; mt < 4; ++mt){ af[mt][0] = LDA(bufb, mt + 4, 0); af[mt][1] = LDA(bufb, mt + 4, 1); }
        __builtin_amdgcn_s_barrier();
        asm volatile("s_waitcnt lgkmcnt(0)" ::: "memory");
        __builtin_amdgcn_sched_barrier(0);
        __builtin_amdgcn_s_setprio(1);
        #pragma unroll
        for (int mt = 0; mt < 4; ++mt)
            #pragma unroll
            for (int nt = 0; nt < 2; ++nt){
                acc[mt+4][nt+2] = MFMA16(af[mt][0], bg[nt][0], acc[mt+4][nt+2], 0, 0, 0);
                acc[mt+4][nt+2] = MFMA16(af[mt][1], bg[nt][1], acc[mt+4][nt+2], 0, 0, 0);
            }
        __builtin_amdgcn_s_setprio(0);
        __builtin_amdgcn_s_barrier();
        // ---- P3: no reads | MFMA -> acc[4..7][0..1] ----
        __builtin_amdgcn_s_setprio(1);
        #pragma unroll
        for (int mt = 0; mt < 4; ++mt)
            #pragma unroll
            for (int nt = 0; nt < 2; ++nt){
                acc[mt+4][nt] = MFMA16(af[mt][0], bf[nt][0], acc[mt+4][nt], 0, 0, 0);
                acc[mt+4][nt] = MFMA16(af[mt][1], bf[nt][1], acc[mt+4][nt], 0, 0, 0);
            }
        __builtin_amdgcn_s_setprio(0);
        __builtin_amdgcn_s_barrier();
        cur ^= 1;
    }

    #pragma unroll
    for (int mt = 0; mt < 8; ++mt){
        int row = bm0 + wm*128 + mt*16 + quad*4;
        #pragma unroll
        for (int nt = 0; nt < 4; ++nt){
            int col = bn0 + wn*64 + nt*16 + l15;
            float bia = bias[col];
            #pragma unroll
            for (int r = 0; r < 4; ++r){
                float v = acc[mt][nt][r] + bia;
                size_t idx = (size_t)(row + r)*ldc + col;
                if constexpr (sizeof(OUT_T) == 2) ((bf16*)C)[idx] = f2bf(v);
                else                              ((float*)C)[idx] = v;
            }
        }
    }
}

// ---------------- RoPE: vectorized (short8 = 4 pairs, q+k per thread) -------
// freq = 10000^(-2p/128) = exp2(-p * log2(10000)/64) — exp2f is 1 HW instr
// (old kernel: powf per pair + 4B scalar accesses -> ~100us, VALU-bound).
__global__ void rope_apply2(bf16* __restrict__ qkv){
    int idx = blockIdx.x * blockDim.x + threadIdx.x;   // (b, s, d8)
    const int d8 = idx & 255;            // d0 = d8*8 in [0,2048)
    const int s  = (idx >> 8) & (S_-1);
    const int b  = idx >> 19;
    const int d0 = d8 * 8;
    const int pbase = (d0 & 127) >> 1;   // pair index within head (0..60)
    bf16* base = qkv + (size_t)(b*S_ + s)*N3_ + d0;
    short8 q = *(short8*)base;
    short8 k = *(short8*)(base + D_);
    const float fs = (float)s;
    #pragma unroll
    for (int i = 0; i < 4; ++i){
        const float freq = exp2f(-0.20762050f * (float)(pbase + i));  // log2(1e4)/64
        const float ang = fs * freq;
        const float c = cosf(ang), sn = sinf(ang);
        float tr = s2f(q[2*i]), ti = s2f(q[2*i+1]);
        q[2*i]   = f2bfs(tr*c - ti*sn);
        q[2*i+1] = f2bfs(tr*sn + ti*c);
        tr = s2f(k[2*i]); ti = s2f(k[2*i+1]);
        k[2*i]   = f2bfs(tr*c - ti*sn);
        k[2*i+1] = f2bfs(tr*sn + ti*c);
    }
    *(short8*)base = q;
    *(short8*)(base + D_) = k;
}

// prefetch register set: by-value struct (SROA-friendly)
struct KV { short8 k0, k1, v0, v1; };

// ---------------- causal flash attention (round-9 kernel, unchanged) --------
__global__ __launch_bounds__(512, 2) void attn(bf16* __restrict__ QKV){
    const int bid  = blockIdx.x;
    const int xcd  = bid & 7, slot = bid >> 3;
    const int bh   = xcd*8 + (slot & 7);
    const int tp   = slot >> 3;                 // 0..7
    const int b = bh >> 4, h = bh & 15;
    const int tid = threadIdx.x;
    const int w = tid >> 6, lane = tid & 63, quad = lane >> 4, l15 = lane & 15;
    bf16* Qp = QKV + (size_t)b*S_*N3_ + h*HD_;
    const bf16* Kp = Qp + D_;
    const bf16* Vp = Qp + 2*D_;
    __shared__ __align__(16) bf16 Ks[2*64*128];
    __shared__ __align__(16) bf16 Vt[2*128*64];
    __shared__ __align__(16) bf16 Pls[8*16*64];

    const int skey = tid >> 3;           // 0..63
    const int st   = tid & 7;            // 32B col group
    const int kswz = (skey & 7) << 4;

    const float scale2 = 0.12751707470412558f;  // (1/sqrt(128)) * log2(e)

    auto load_kv = [&](int kb) -> KV {
        KV r;
        const char* krow = (const char*)&Kp[(size_t)(kb + skey)*N3_];
        const char* vrow = (const char*)&Vp[(size_t)(kb + skey)*N3_];
        r.k0 = *(const short8*)(krow + st*32);
        r.k1 = *(const short8*)(krow + st*32 + 16);
        r.v0 = *(const short8*)(vrow + st*32);
        r.v1 = *(const short8*)(vrow + st*32 + 16);
        return r;
    };
    auto stage_write = [&](int pbuf, KV x){
        char* kd = (char*)Ks + pbuf*16384;
        char* vd = (char*)Vt + pbuf*16384;
        *(short8*)(kd + ((skey*256 + st*32     ) ^ kswz)) = x.k0;
        *(short8*)(kd + ((skey*256 + st*32 + 16) ^ kswz)) = x.k1;
        #pragma unroll
        for (int g = 0; g < 2; ++g){
            short8 vv = g ? x.v1 : x.v0;
            #pragma unroll
            for (int j = 0; j < 8; ++j){
                const int d = st*16 + g*8 + j;   // d&7==j, (d>>4)&7==st
                *(short*)(vd + ((d*128 + skey*2) ^ (((j ^ st) & 7) << 4))) = vv[j];
            }
        }
    };

    int pb = 0;
    KV a = load_kv(0);

    for (int half = 0; half < 2; ++half){
        const int t = half ? (15 - tp) : tp;
        const int qrow = t*128 + w*16 + l15;
        short8 qf[4];
        #pragma unroll
        for (int kc = 0; kc < 4; ++kc)
            qf[kc] = *(const short8*)&Qp[(size_t)qrow*N3_ + kc*32 + quad*8];

        float4_ accO[8] = {};
        float m_i[4], l_i[4];
        #pragma unroll
        for (int r = 0; r < 4; ++r){ m_i[r] = -3.0e38f; l_i[r] = 0.0f; }
        const int rbase = t*128 + w*16 + quad*4;
        const int wmin  = t*128 + w*16;
        const int wmax  = wmin + 15;
        const int nch = 2*t + 2;
        const int nch1 = 32 - 2*tp;
        auto kb_of = [&](int s){ return (half ? (nch - 1 - s) : s) * 64; };

        auto compute = [&](int pbuf, int kb){
            const char* kbs = (const char*)Ks + pbuf*16384;
            const char* vbs = (const char*)Vt + pbuf*16384;
            float4_ sacc[4] = {};
            __builtin_amdgcn_s_setprio(1);
            #pragma unroll
            for (int kc = 0; kc < 4; ++kc)
                #pragma unroll
                for (int nt = 0; nt < 4; ++nt){
                    short8 kf = *(const short8*)(kbs +
                        (((nt*16 + l15)*256 + kc*64 + quad*16) ^ ((l15 & 7) << 4)));
                    sacc[nt] = MFMA16(qf[kc], kf, sacc[nt], 0, 0, 0);
                }
            __builtin_amdgcn_s_setprio(0);

            if (kb + 63 > wmin){
                #pragma unroll
                for (int nt = 0; nt < 4; ++nt){
                    const int j = kb + nt*16 + l15;
                    #pragma unroll
                    for (int r = 0; r < 4; ++r){
                        float v = sacc[nt][r] * scale2;
                        sacc[nt][r] = (j > rbase + r) ? -3.0e38f : v;
                    }
                }
            } else {
                #pragma unroll
                for (int nt = 0; nt < 4; ++nt)
                    #pragma unroll
                    for (int r = 0; r < 4; ++r) sacc[nt][r] *= scale2;
            }

            float tmax[4];
            #pragma unroll
            for (int r = 0; r < 4; ++r)
                tmax[r] = fmaxf(fmaxf(sacc[0][r], sacc[1][r]),
                                fmaxf(sacc[2][r], sacc[3][r]));
            int stable = (tmax[0] <= m_i[0] + 8.0f) & (tmax[1] <= m_i[1] + 8.0f) &
                         (tmax[2] <= m_i[2] + 8.0f) & (tmax[3] <= m_i[3] + 8.0f);
            if (__all(stable)){
                #pragma unroll
                for (int r = 0; r < 4; ++r){
                    float s = 0.0f;
                    #pragma unroll
                    for (int nt = 0; nt < 4; ++nt){
                        float p = exp2f(sacc[nt][r] - m_i[r]);
                        sacc[nt][r] = p; s += p;
                    }
                    l_i[r] += s;
                }
            } else {
                float alpha[4];
                #pragma unroll
                for (int r = 0; r < 4; ++r){
                    float v = fmaxf(tmax[r], m_i[r]);
                    #pragma unroll
                    for (int off = 1; off < 16; off <<= 1) v = fmaxf(v, __shfl_xor(v, off, 64));
                    alpha[r] = exp2f(m_i[r] - v);
                    m_i[r] = v;
                    float s = 0.0f;
                    #pragma unroll
                    for (int nt = 0; nt < 4; ++nt){
                        float p = exp2f(sacc[nt][r] - v);
                        sacc[nt][r] = p; s += p;
                    }
                    l_i[r] = l_i[r]*alpha[r] + s;
                }
                #pragma unroll
                for (int dt = 0; dt < 8; ++dt)
                    #pragma unroll
                    for (int r = 0; r < 4; ++r) accO[dt][r] *= alpha[r];
            }

            #pragma unroll
            for (int nt = 0; nt < 4; ++nt)
                #pragma unroll
                for (int r = 0; r < 4; ++r){
                    const int prow = quad*4 + r;
                    const int swp = ((prow & 7) ^ (((prow >> 3) & 1) << 1)) << 4;
                    *(short*)((char*)Pls + ((w*2048 + prow*128 + (nt*16 + l15)*2)
                                            ^ swp)) = f2bfs(sacc[nt][r]);
                }
            __asm volatile("s_waitcnt lgkmcnt(0)" ::: "memory");
            const int swr = ((l15 & 7) ^ (((l15 >> 3) & 1) << 1)) << 4;
            short8 pf0 = *(const short8*)((const char*)Pls +
                ((w*2048 + l15*128      + quad*16) ^ swr));
            short8 pf1 = *(const short8*)((const char*)Pls +
                ((w*2048 + l15*128 + 64 + quad*16) ^ swr));

            __builtin_amdgcn_s_setprio(1);
            #pragma unroll
            for (int dt = 0; dt < 8; ++dt){
                const int rb = (dt*16 + l15)*128;
                const int sw2 = (((l15 & 7) ^ dt) & 7) << 4;
                short8 vf0 = *(const short8*)(vbs + ((rb      + quad*16) ^ sw2));
                short8 vf1 = *(const short8*)(vbs + ((rb + 64 + quad*16) ^ sw2));
                accO[dt] = MFMA16(pf0, vf0, accO[dt], 0, 0, 0);
                accO[dt] = MFMA16(pf1, vf1, accO[dt], 0, 0, 0);
            }
            __builtin_amdgcn_s_setprio(0);
        };

        for (int s = 0; s < nch; ++s){
            stage_write(pb, a);
            if (s + 1 < nch)      a = load_kv(kb_of(s + 1));
            else if (half == 0)   a = load_kv((nch1 - 1) * 64);
            asm volatile("s_waitcnt lgkmcnt(0)" ::: "memory");
            __builtin_amdgcn_s_barrier();
            { const int kb = kb_of(s); if (kb <= wmax) compute(pb, kb); }
            pb ^= 1;
        }

        float inv[4];
        #pragma unroll
        for (int r = 0; r < 4; ++r){
            float s = l_i[r];
            #pragma unroll
            for (int off = 1; off < 16; off <<= 1) s += __shfl_xor(s, off, 64);
            inv[r] = 1.0f / s;
        }
        #pragma unroll
        for (int dt = 0; dt < 8; ++dt)
            #pragma unroll
            for (int r = 0; r < 4; ++r){
                int s = t*128 + w*16 + quad*4 + r;
                int d = dt*16 + l15;
                Qp[(size_t)s*N3_ + d] = f2bf(accO[dt][r]*inv[r]);
            }
    }
}

// ---------------- launch ----------------
extern "C" void kernel_launch(void* const* d_in, const int* in_sizes, int n_in,
                              void* d_out, int out_size, void* d_ws, size_t ws_size,
                              hipStream_t stream){
    const float* x    = (const float*)d_in[0];
    const float* Wqkv = (const float*)d_in[1];
    const float* bqkv = (const float*)d_in[2];
    const float* Wo   = (const float*)d_in[3];
    const float* bo   = (const float*)d_in[4];
    float* out = (float*)d_out;
    char* ws = (char*)d_ws;

    // qkv is the only mandatory buffer: 8192 x 6144 bf16 = 100,663,296 B (96 MiB)
    bf16* qkv = (bf16*)(ws + 0);

    // Fast path needs additionally: xb 32 MiB + wqkvb 24 MiB + wob 8 MiB -> 160 MiB total
    const size_t OFF_XB = 100663296, OFF_WQ = 134217728, OFF_WO = 159383552;
    const bool big = (ws_size >= (size_t)167772160);

    if (big){
        bf16* xb    = (bf16*)(ws + OFF_XB);
        bf16* wqkvb = (bf16*)(ws + OFF_WQ);
        bf16* wob   = (bf16*)(ws + OFF_WO);
        long n8;
        n8 = (long)M_*D_/8;   cast_f32_bf16<<<(n8+255)/256, 256, 0, stream>>>(x, xb, n8);
        n8 = (long)N3_*D_/8;  cast_f32_bf16<<<(n8+255)/256, 256, 0, stream>>>(Wqkv, wqkvb, n8);
        n8 = (long)D_*D_/8;   cast_f32_bf16<<<(n8+255)/256, 256, 0, stream>>>(Wo, wob, n8);
        gemm256<bf16><<<dim3(N3_/256, M_/256), 512, 0, stream>>>(
            xb, D_, wqkvb, D_, bqkv, qkv, N3_, D_);
        rope_apply2<<<(B_*S_*D_/8)/256, 256, 0, stream>>>(qkv);
        attn<<<dim3(512), 512, 0, stream>>>(qkv);
        gemm256<float><<<dim3(D_/256, M_/256), 512, 0, stream>>>(
            qkv, N3_, wob, D_, bo, out, D_, D_);
    } else {
        // compact path: fp32 inputs converted during GEMM staging; 96 MiB workspace
        gemm_bt<float,float,bf16><<<dim3(N3_/128, M_/128), 256, 0, stream>>>(
            x, D_, Wqkv, D_, bqkv, qkv, N3_, D_);
        rope_apply2<<<(B_*S_*D_/8)/256, 256, 0, stream>>>(qkv);
        attn<<<dim3(512), 512, 0, stream>>>(qkv);
        gemm_bt<bf16,float,float><<<dim3(D_/128, M_/128), 256, 0, stream>>>(
            qkv, N3_, Wo, D_, bo, out, D_, D_);
    }
}

// Round 13
// 589.776 us; speedup vs baseline: 2.0512x; 1.0029x over previous
//
#include <hip/hip_runtime.h>
#include <hip/hip_bf16.h>
#include <math.h>

// Problem constants
#define B_   4
#define S_   2048
#define D_   2048
#define H_   16
#define HD_  128
#define N3_  6144   // 3*D
#define M_   8192   // B*S

typedef __attribute__((ext_vector_type(8))) short  short8;
typedef __attribute__((ext_vector_type(4))) float  float4_;

using bf16 = __hip_bfloat16;

static __device__ __forceinline__ float bf2f(bf16 v){ return __bfloat162float(v); }
static __device__ __forceinline__ bf16  f2bf(float v){ return __float2bfloat16(v); }
static __device__ __forceinline__ short f2bfs(float v){
    return (short)__builtin_bit_cast(unsigned short, __float2bfloat16(v));
}
static __device__ __forceinline__ float s2f(short v){
    return __bfloat162float(__builtin_bit_cast(bf16, (unsigned short)v));
}

// load 8 elements as bf16 short8 — overloaded on source dtype
static __device__ __forceinline__ short8 load8(const bf16* p){ return *(const short8*)p; }
static __device__ __forceinline__ short8 load8(const float* p){
    float4_ a = *(const float4_*)p;
    float4_ b = *(const float4_*)(p + 4);
    short8 r;
    r[0]=f2bfs(a[0]); r[1]=f2bfs(a[1]); r[2]=f2bfs(a[2]); r[3]=f2bfs(a[3]);
    r[4]=f2bfs(b[0]); r[5]=f2bfs(b[1]); r[6]=f2bfs(b[2]); r[7]=f2bfs(b[3]);
    return r;
}

// async global->LDS 16B copy (global_load_lds_dwordx4)
static __device__ __forceinline__ void cp16_g2l(const void* g, void* l){
    __builtin_amdgcn_global_load_lds((const __attribute__((address_space(1))) void*)g,
                                     (__attribute__((address_space(3))) void*)l,
                                     16, 0, 0);
}

#define MFMA16 __builtin_amdgcn_mfma_f32_16x16x32_bf16

// ---------------- cast fp32 -> bf16 (fast path only) ----------------
__global__ void cast_f32_bf16(const float* __restrict__ in, bf16* __restrict__ out, long n8){
    long i = (long)blockIdx.x * blockDim.x + threadIdx.x;
    if (i >= n8) return;
    *((short8*)out + i) = load8(in + 8*i);
}

// ---------------- legacy 128-tile GEMM (compact path only) ----------------
template<typename AT, typename BT, typename OUT_T>
__global__ __launch_bounds__(256) void gemm_bt(const AT* __restrict__ A, int lda,
                                               const BT* __restrict__ Bt, int ldb,
                                               const float* __restrict__ bias,
                                               OUT_T* __restrict__ C, int ldc, int Kdim){
    __shared__ __align__(16) bf16 As[128*32];
    __shared__ __align__(16) bf16 Bs[128*32];
    const int tid  = threadIdx.x;
    const int lane = tid & 63;
    const int w    = tid >> 6;
    const int wm   = w >> 1, wn = w & 1;
    const int quad = lane >> 4, l15 = lane & 15;
    const int bn0  = blockIdx.x * 128, bm0 = blockIdx.y * 128;
    const int srow = tid >> 2;          // 0..63
    const int scol = (tid & 3) * 8;     // 0,8,16,24

    float4_ acc[4][4] = {};

    for (int k0 = 0; k0 < Kdim; k0 += 32){
        __syncthreads();
        #pragma unroll
        for (int half = 0; half < 2; ++half){
            int r = half*64 + srow;
            *(short8*)&As[r*32 + scol] = load8(&A[(size_t)(bm0 + r)*lda + k0 + scol]);
            *(short8*)&Bs[r*32 + scol] = load8(&Bt[(size_t)(bn0 + r)*ldb + k0 + scol]);
        }
        __syncthreads();
        short8 af[4], bfr[4];
        #pragma unroll
        for (int mt = 0; mt < 4; ++mt) af[mt]  = *(const short8*)&As[(wm*64 + mt*16 + l15)*32 + quad*8];
        #pragma unroll
        for (int nt = 0; nt < 4; ++nt) bfr[nt] = *(const short8*)&Bs[(wn*64 + nt*16 + l15)*32 + quad*8];
        #pragma unroll
        for (int mt = 0; mt < 4; ++mt)
            #pragma unroll
            for (int nt = 0; nt < 4; ++nt)
                acc[mt][nt] = MFMA16(af[mt], bfr[nt], acc[mt][nt], 0, 0, 0);
    }

    #pragma unroll
    for (int mt = 0; mt < 4; ++mt){
        int row = bm0 + wm*64 + mt*16 + quad*4;
        #pragma unroll
        for (int nt = 0; nt < 4; ++nt){
            int col = bn0 + wn*64 + nt*16 + l15;
            float bia = bias[col];
            #pragma unroll
            for (int r = 0; r < 4; ++r){
                float v = acc[mt][nt][r] + bia;
                size_t idx = (size_t)(row + r)*ldc + col;
                if constexpr (sizeof(OUT_T) == 2) ((bf16*)C)[idx] = f2bf(v);
                else                              ((float*)C)[idx] = v;
            }
        }
    }
}

// ---------------- 256-tile counted-vmcnt bf16 GEMM ----------------
// BM=BN=256, BK=64, 512 thr = 8 waves (2M x 4N), acc[8][4]. LDS 128 KiB
// double-buffered; staging via global_load_lds w=16, linear dest +
// pre-swizzled global source; ds_read same XOR (bank conflicts = 0, r9).
// Counted wait: vmcnt(8) once per tile. 1D grid + XCD-chunked block
// decode (T1): xcd = bid&7 owns cols [xcd*cpx, (xcd+1)*cpx) -> B col-panels
// (1-3 MB) stay resident in that XCD's L2; A row-panels served from L3.
template<typename OUT_T>
__global__ __launch_bounds__(512, 2) void gemm256(const bf16* __restrict__ A, int lda,
                                                  const bf16* __restrict__ Bt, int ldb,
                                                  const float* __restrict__ bias,
                                                  OUT_T* __restrict__ C, int ldc, int Kdim,
                                                  int ncols){
    __shared__ __align__(16) char lds[131072];
    const int tid  = threadIdx.x;
    const int lane = tid & 63;
    const int w    = tid >> 6;            // 0..7
    const int wm   = w >> 2, wn = w & 3;  // 2 x 4
    const int quad = lane >> 4, l15 = lane & 15;
    const int sw   = l15 & 7;
    // XCD-chunked decode (ncols % 8 == 0 for both call sites)
    const int bid = blockIdx.x;
    const int xcd = bid & 7, idx = bid >> 3;
    const int cpx = ncols >> 3;
    const int col = xcd*cpx + (idx % cpx);
    const int row = idx / cpx;
    const int bn0 = col * 256, bm0 = row * 256;

    const int g1 = tid, g2 = tid + 512;
    const int r1 = g1 >> 3, c1 = g1 & 7;
    const int r2 = g2 >> 3, c2 = g2 & 7;
    const int d1 = g1 * 16, d2 = g2 * 16;
    const char* pA0g1 = (const char*)(A  + (size_t)(bm0 +       r1)*lda + ((c1 ^ (r1 & 7)) << 3));
    const char* pA0g2 = (const char*)(A  + (size_t)(bm0 +       r2)*lda + ((c2 ^ (r2 & 7)) << 3));
    const char* pA1g1 = (const char*)(A  + (size_t)(bm0 + 128 + r1)*lda + ((c1 ^ (r1 & 7)) << 3));
    const char* pA1g2 = (const char*)(A  + (size_t)(bm0 + 128 + r2)*lda + ((c2 ^ (r2 & 7)) << 3));
    const char* pB0g1 = (const char*)(Bt + (size_t)(bn0 +       r1)*ldb + ((c1 ^ (r1 & 7)) << 3));
    const char* pB0g2 = (const char*)(Bt + (size_t)(bn0 +       r2)*ldb + ((c2 ^ (r2 & 7)) << 3));
    const char* pB1g1 = (const char*)(Bt + (size_t)(bn0 + 128 + r1)*ldb + ((c1 ^ (r1 & 7)) << 3));
    const char* pB1g2 = (const char*)(Bt + (size_t)(bn0 + 128 + r2)*ldb + ((c2 ^ (r2 & 7)) << 3));

    auto STAGE = [&](int bufb, int kby){
        cp16_g2l(pA0g1 + kby, lds + bufb +         d1);
        cp16_g2l(pA0g2 + kby, lds + bufb +         d2);
        cp16_g2l(pA1g1 + kby, lds + bufb + 16384 + d1);
        cp16_g2l(pA1g2 + kby, lds + bufb + 16384 + d2);
        cp16_g2l(pB0g1 + kby, lds + bufb + 32768 + d1);
        cp16_g2l(pB0g2 + kby, lds + bufb + 32768 + d2);
        cp16_g2l(pB1g1 + kby, lds + bufb + 49152 + d1);
        cp16_g2l(pB1g2 + kby, lds + bufb + 49152 + d2);
    };

    const int abase = (wm ? 16384 : 0);
    const int bbase = 32768 + ((wn >> 1) ? 16384 : 0);
    const int brow0 = (wn & 1) * 64;
    auto LDA = [&](int bufb, int mt, int kk) -> short8 {
        return *(const short8*)(lds + bufb + abase + (mt*16 + l15)*128
                                + (((kk*4 + quad) ^ sw) << 4));
    };
    auto LDB = [&](int bufb, int nt, int kk) -> short8 {
        return *(const short8*)(lds + bufb + bbase + (brow0 + nt*16 + l15)*128
                                + (((kk*4 + quad) ^ sw) << 4));
    };

    float4_ acc[8][4] = {};
    const int NT = Kdim >> 6;

    STAGE(0, 0);
    asm volatile("s_waitcnt vmcnt(0)" ::: "memory");
    __builtin_amdgcn_s_barrier();

    int cur = 0;
    for (int kt = 0; kt < NT; ++kt){
        const int bufb = cur << 16;
        if (kt + 1 < NT){
            STAGE(bufb ^ 65536, (kt + 1) << 7);
            asm volatile("s_waitcnt vmcnt(8)" ::: "memory");
        } else {
            asm volatile("s_waitcnt vmcnt(0)" ::: "memory");
        }
        __builtin_amdgcn_s_barrier();

        short8 af[4][2], bf[2][2], bg[2][2];
        // ---- P0: read af(mt0-3) + bf(nt0-1) | bar | MFMA -> acc[0..3][0..1] ----
        #pragma unroll
        for (int mt = 0; mt < 4; ++mt){ af[mt][0] = LDA(bufb, mt, 0); af[mt][1] = LDA(bufb, mt, 1); }
        #pragma unroll
        for (int nt = 0; nt < 2; ++nt){ bf[nt][0] = LDB(bufb, nt, 0); bf[nt][1] = LDB(bufb, nt, 1); }
        __builtin_amdgcn_s_barrier();
        asm volatile("s_waitcnt lgkmcnt(0)" ::: "memory");
        __builtin_amdgcn_sched_barrier(0);
        __builtin_amdgcn_s_setprio(1);
        #pragma unroll
        for (int mt = 0; mt < 4; ++mt)
            #pragma unroll
            for (int nt = 0; nt < 2; ++nt){
                acc[mt][nt] = MFMA16(af[mt][0], bf[nt][0], acc[mt][nt], 0, 0, 0);
                acc[mt][nt] = MFMA16(af[mt][1], bf[nt][1], acc[mt][nt], 0, 0, 0);
            }
        __builtin_amdgcn_s_setprio(0);
        __builtin_amdgcn_s_barrier();
        // ---- P1: read bg(nt2-3) | bar | MFMA -> acc[0..3][2..3] ----
        #pragma unroll
        for (int nt = 0; nt < 2; ++nt){ bg[nt][0] = LDB(bufb, nt + 2, 0); bg[nt][1] = LDB(bufb, nt + 2, 1); }
        __builtin_amdgcn_s_barrier();
        asm volatile("s_waitcnt lgkmcnt(0)" ::: "memory");
        __builtin_amdgcn_sched_barrier(0);
        __builtin_amdgcn_s_setprio(1);
        #pragma unroll
        for (int mt = 0; mt < 4; ++mt)
            #pragma unroll
            for (int nt = 0; nt < 2; ++nt){
                acc[mt][nt+2] = MFMA16(af[mt][0], bg[nt][0], acc[mt][nt+2], 0, 0, 0);
                acc[mt][nt+2] = MFMA16(af[mt][1], bg[nt][1], acc[mt][nt+2], 0, 0, 0);
            }
        __builtin_amdgcn_s_setprio(0);
        __builtin_amdgcn_s_barrier();
        // ---- P2: read af(mt4-7) | bar | MFMA -> acc[4..7][2..3] ----
        #pragma unroll
        for (int mt = 0; mt < 4; ++mt){ af[mt][0] = LDA(bufb, mt + 4, 0); af[mt][1] = LDA(bufb, mt + 4, 1); }
        __builtin_amdgcn_s_barrier();
        asm volatile("s_waitcnt lgkmcnt(0)" ::: "memory");
        __builtin_amdgcn_sched_barrier(0);
        __builtin_amdgcn_s_setprio(1);
        #pragma unroll
        for (int mt = 0; mt < 4; ++mt)
            #pragma unroll
            for (int nt = 0; nt < 2; ++nt){
                acc[mt+4][nt+2] = MFMA16(af[mt][0], bg[nt][0], acc[mt+4][nt+2], 0, 0, 0);
                acc[mt+4][nt+2] = MFMA16(af[mt][1], bg[nt][1], acc[mt+4][nt+2], 0, 0, 0);
            }
        __builtin_amdgcn_s_setprio(0);
        __builtin_amdgcn_s_barrier();
        // ---- P3: no reads | MFMA -> acc[4..7][0..1] ----
        __builtin_amdgcn_s_setprio(1);
        #pragma unroll
        for (int mt = 0; mt < 4; ++mt)
            #pragma unroll
            for (int nt = 0; nt < 2; ++nt){
                acc[mt+4][nt] = MFMA16(af[mt][0], bf[nt][0], acc[mt+4][nt], 0, 0, 0);
                acc[mt+4][nt] = MFMA16(af[mt][1], bf[nt][1], acc[mt+4][nt], 0, 0, 0);
            }
        __builtin_amdgcn_s_setprio(0);
        __builtin_amdgcn_s_barrier();
        cur ^= 1;
    }

    #pragma unroll
    for (int mt = 0; mt < 8; ++mt){
        int rr = bm0 + wm*128 + mt*16 + quad*4;
        #pragma unroll
        for (int nt = 0; nt < 4; ++nt){
            int cc = bn0 + wn*64 + nt*16 + l15;
            float bia = bias[cc];
            #pragma unroll
            for (int r = 0; r < 4; ++r){
                float v = acc[mt][nt][r] + bia;
                size_t idx2 = (size_t)(rr + r)*ldc + cc;
                if constexpr (sizeof(OUT_T) == 2) ((bf16*)C)[idx2] = f2bf(v);
                else                              ((float*)C)[idx2] = v;
            }
        }
    }
}

// ---------------- RoPE: LDS trig table per (b,s) row -----------------------
// Block = one (b,s) row, 256 threads. Threads 0-63 compute the row's 64
// cos/sin via native __sinf/__cosf (v_sin/v_cos) -> LDS; all threads then
// apply rotations with short8 vector accesses. Trig count: 8.4M libm calls
// -> 0.52M native pairs (16x fewer, ~10x cheaper); kernel becomes mem-bound.
__global__ __launch_bounds__(256) void rope_apply3(bf16* __restrict__ qkv){
    __shared__ float cs[64], sn[64];
    const int bs  = blockIdx.x;          // b*S_ + s
    const int s   = bs & (S_-1);
    const int tid = threadIdx.x;
    if (tid < 64){
        const float freq = exp2f(-0.20762050f * (float)tid);  // log2(1e4)/64
        const float ang  = (float)s * freq;
        sn[tid] = __sinf(ang);
        cs[tid] = __cosf(ang);
    }
    __syncthreads();
    const int d0 = tid * 8;
    const int pb = (d0 & 127) >> 1;      // pair base within head: 4*tid mod 64
    bf16* base = qkv + (size_t)bs*N3_ + d0;
    short8 q = *(short8*)base;
    short8 k = *(short8*)(base + D_);
    #pragma unroll
    for (int i = 0; i < 4; ++i){
        const float c = cs[pb + i], s2 = sn[pb + i];
        float tr = s2f(q[2*i]), ti = s2f(q[2*i+1]);
        q[2*i]   = f2bfs(tr*c - ti*s2);
        q[2*i+1] = f2bfs(tr*s2 + ti*c);
        tr = s2f(k[2*i]); ti = s2f(k[2*i+1]);
        k[2*i]   = f2bfs(tr*c - ti*s2);
        k[2*i+1] = f2bfs(tr*s2 + ti*c);
    }
    *(short8*)base = q;
    *(short8*)(base + D_) = k;
}

// prefetch register set: by-value struct (SROA-friendly)
struct KV { short8 k0, k1, v0, v1; };

// ---------------- causal flash attention (round-9 kernel, unchanged) --------
__global__ __launch_bounds__(512, 2) void attn(bf16* __restrict__ QKV){
    const int bid  = blockIdx.x;
    const int xcd  = bid & 7, slot = bid >> 3;
    const int bh   = xcd*8 + (slot & 7);
    const int tp   = slot >> 3;                 // 0..7
    const int b = bh >> 4, h = bh & 15;
    const int tid = threadIdx.x;
    const int w = tid >> 6, lane = tid & 63, quad = lane >> 4, l15 = lane & 15;
    bf16* Qp = QKV + (size_t)b*S_*N3_ + h*HD_;
    const bf16* Kp = Qp + D_;
    const bf16* Vp = Qp + 2*D_;
    __shared__ __align__(16) bf16 Ks[2*64*128];
    __shared__ __align__(16) bf16 Vt[2*128*64];
    __shared__ __align__(16) bf16 Pls[8*16*64];

    const int skey = tid >> 3;           // 0..63
    const int st   = tid & 7;            // 32B col group
    const int kswz = (skey & 7) << 4;

    const float scale2 = 0.12751707470412558f;  // (1/sqrt(128)) * log2(e)

    auto load_kv = [&](int kb) -> KV {
        KV r;
        const char* krow = (const char*)&Kp[(size_t)(kb + skey)*N3_];
        const char* vrow = (const char*)&Vp[(size_t)(kb + skey)*N3_];
        r.k0 = *(const short8*)(krow + st*32);
        r.k1 = *(const short8*)(krow + st*32 + 16);
        r.v0 = *(const short8*)(vrow + st*32);
        r.v1 = *(const short8*)(vrow + st*32 + 16);
        return r;
    };
    auto stage_write = [&](int pbuf, KV x){
        char* kd = (char*)Ks + pbuf*16384;
        char* vd = (char*)Vt + pbuf*16384;
        *(short8*)(kd + ((skey*256 + st*32     ) ^ kswz)) = x.k0;
        *(short8*)(kd + ((skey*256 + st*32 + 16) ^ kswz)) = x.k1;
        #pragma unroll
        for (int g = 0; g < 2; ++g){
            short8 vv = g ? x.v1 : x.v0;
            #pragma unroll
            for (int j = 0; j < 8; ++j){
                const int d = st*16 + g*8 + j;   // d&7==j, (d>>4)&7==st
                *(short*)(vd + ((d*128 + skey*2) ^ (((j ^ st) & 7) << 4))) = vv[j];
            }
        }
    };

    int pb = 0;
    KV a = load_kv(0);

    for (int half = 0; half < 2; ++half){
        const int t = half ? (15 - tp) : tp;
        const int qrow = t*128 + w*16 + l15;
        short8 qf[4];
        #pragma unroll
        for (int kc = 0; kc < 4; ++kc)
            qf[kc] = *(const short8*)&Qp[(size_t)qrow*N3_ + kc*32 + quad*8];

        float4_ accO[8] = {};
        float m_i[4], l_i[4];
        #pragma unroll
        for (int r = 0; r < 4; ++r){ m_i[r] = -3.0e38f; l_i[r] = 0.0f; }
        const int rbase = t*128 + w*16 + quad*4;
        const int wmin  = t*128 + w*16;
        const int wmax  = wmin + 15;
        const int nch = 2*t + 2;
        const int nch1 = 32 - 2*tp;
        auto kb_of = [&](int s){ return (half ? (nch - 1 - s) : s) * 64; };

        auto compute = [&](int pbuf, int kb){
            const char* kbs = (const char*)Ks + pbuf*16384;
            const char* vbs = (const char*)Vt + pbuf*16384;
            float4_ sacc[4] = {};
            __builtin_amdgcn_s_setprio(1);
            #pragma unroll
            for (int kc = 0; kc < 4; ++kc)
                #pragma unroll
                for (int nt = 0; nt < 4; ++nt){
                    short8 kf = *(const short8*)(kbs +
                        (((nt*16 + l15)*256 + kc*64 + quad*16) ^ ((l15 & 7) << 4)));
                    sacc[nt] = MFMA16(qf[kc], kf, sacc[nt], 0, 0, 0);
                }
            __builtin_amdgcn_s_setprio(0);

            if (kb + 63 > wmin){
                #pragma unroll
                for (int nt = 0; nt < 4; ++nt){
                    const int j = kb + nt*16 + l15;
                    #pragma unroll
                    for (int r = 0; r < 4; ++r){
                        float v = sacc[nt][r] * scale2;
                        sacc[nt][r] = (j > rbase + r) ? -3.0e38f : v;
                    }
                }
            } else {
                #pragma unroll
                for (int nt = 0; nt < 4; ++nt)
                    #pragma unroll
                    for (int r = 0; r < 4; ++r) sacc[nt][r] *= scale2;
            }

            float tmax[4];
            #pragma unroll
            for (int r = 0; r < 4; ++r)
                tmax[r] = fmaxf(fmaxf(sacc[0][r], sacc[1][r]),
                                fmaxf(sacc[2][r], sacc[3][r]));
            int stable = (tmax[0] <= m_i[0] + 8.0f) & (tmax[1] <= m_i[1] + 8.0f) &
                         (tmax[2] <= m_i[2] + 8.0f) & (tmax[3] <= m_i[3] + 8.0f);
            if (__all(stable)){
                #pragma unroll
                for (int r = 0; r < 4; ++r){
                    float s = 0.0f;
                    #pragma unroll
                    for (int nt = 0; nt < 4; ++nt){
                        float p = exp2f(sacc[nt][r] - m_i[r]);
                        sacc[nt][r] = p; s += p;
                    }
                    l_i[r] += s;
                }
            } else {
                float alpha[4];
                #pragma unroll
                for (int r = 0; r < 4; ++r){
                    float v = fmaxf(tmax[r], m_i[r]);
                    #pragma unroll
                    for (int off = 1; off < 16; off <<= 1) v = fmaxf(v, __shfl_xor(v, off, 64));
                    alpha[r] = exp2f(m_i[r] - v);
                    m_i[r] = v;
                    float s = 0.0f;
                    #pragma unroll
                    for (int nt = 0; nt < 4; ++nt){
                        float p = exp2f(sacc[nt][r] - v);
                        sacc[nt][r] = p; s += p;
                    }
                    l_i[r] = l_i[r]*alpha[r] + s;
                }
                #pragma unroll
                for (int dt = 0; dt < 8; ++dt)
                    #pragma unroll
                    for (int r = 0; r < 4; ++r) accO[dt][r] *= alpha[r];
            }

            #pragma unroll
            for (int nt = 0; nt < 4; ++nt)
                #pragma unroll
                for (int r = 0; r < 4; ++r){
                    const int prow = quad*4 + r;
                    const int swp = ((prow & 7) ^ (((prow >> 3) & 1) << 1)) << 4;
                    *(short*)((char*)Pls + ((w*2048 + prow*128 + (nt*16 + l15)*2)
                                            ^ swp)) = f2bfs(sacc[nt][r]);
                }
            __asm volatile("s_waitcnt lgkmcnt(0)" ::: "memory");
            const int swr = ((l15 & 7) ^ (((l15 >> 3) & 1) << 1)) << 4;
            short8 pf0 = *(const short8*)((const char*)Pls +
                ((w*2048 + l15*128      + quad*16) ^ swr));
            short8 pf1 = *(const short8*)((const char*)Pls +
                ((w*2048 + l15*128 + 64 + quad*16) ^ swr));

            __builtin_amdgcn_s_setprio(1);
            #pragma unroll
            for (int dt = 0; dt < 8; ++dt){
                const int rb = (dt*16 + l15)*128;
                const int sw2 = (((l15 & 7) ^ dt) & 7) << 4;
                short8 vf0 = *(const short8*)(vbs + ((rb      + quad*16) ^ sw2));
                short8 vf1 = *(const short8*)(vbs + ((rb + 64 + quad*16) ^ sw2));
                accO[dt] = MFMA16(pf0, vf0, accO[dt], 0, 0, 0);
                accO[dt] = MFMA16(pf1, vf1, accO[dt], 0, 0, 0);
            }
            __builtin_amdgcn_s_setprio(0);
        };

        for (int s = 0; s < nch; ++s){
            stage_write(pb, a);
            if (s + 1 < nch)      a = load_kv(kb_of(s + 1));
            else if (half == 0)   a = load_kv((nch1 - 1) * 64);
            asm volatile("s_waitcnt lgkmcnt(0)" ::: "memory");
            __builtin_amdgcn_s_barrier();
            { const int kb = kb_of(s); if (kb <= wmax) compute(pb, kb); }
            pb ^= 1;
        }

        float inv[4];
        #pragma unroll
        for (int r = 0; r < 4; ++r){
            float s = l_i[r];
            #pragma unroll
            for (int off = 1; off < 16; off <<= 1) s += __shfl_xor(s, off, 64);
            inv[r] = 1.0f / s;
        }
        #pragma unroll
        for (int dt = 0; dt < 8; ++dt)
            #pragma unroll
            for (int r = 0; r < 4; ++r){
                int s = t*128 + w*16 + quad*4 + r;
                int d = dt*16 + l15;
                Qp[(size_t)s*N3_ + d] = f2bf(accO[dt][r]*inv[r]);
            }
    }
}

// ---------------- launch ----------------
extern "C" void kernel_launch(void* const* d_in, const int* in_sizes, int n_in,
                              void* d_out, int out_size, void* d_ws, size_t ws_size,
                              hipStream_t stream){
    const float* x    = (const float*)d_in[0];
    const float* Wqkv = (const float*)d_in[1];
    const float* bqkv = (const float*)d_in[2];
    const float* Wo   = (const float*)d_in[3];
    const float* bo   = (const float*)d_in[4];
    float* out = (float*)d_out;
    char* ws = (char*)d_ws;

    // qkv is the only mandatory buffer: 8192 x 6144 bf16 = 100,663,296 B (96 MiB)
    bf16* qkv = (bf16*)(ws + 0);

    // Fast path needs additionally: xb 32 MiB + wqkvb 24 MiB + wob 8 MiB -> 160 MiB total
    const size_t OFF_XB = 100663296, OFF_WQ = 134217728, OFF_WO = 159383552;
    const bool big = (ws_size >= (size_t)167772160);

    if (big){
        bf16* xb    = (bf16*)(ws + OFF_XB);
        bf16* wqkvb = (bf16*)(ws + OFF_WQ);
        bf16* wob   = (bf16*)(ws + OFF_WO);
        long n8;
        n8 = (long)M_*D_/8;   cast_f32_bf16<<<(n8+255)/256, 256, 0, stream>>>(x, xb, n8);
        n8 = (long)N3_*D_/8;  cast_f32_bf16<<<(n8+255)/256, 256, 0, stream>>>(Wqkv, wqkvb, n8);
        n8 = (long)D_*D_/8;   cast_f32_bf16<<<(n8+255)/256, 256, 0, stream>>>(Wo, wob, n8);
        gemm256<bf16><<<dim3((N3_/256)*(M_/256)), 512, 0, stream>>>(
            xb, D_, wqkvb, D_, bqkv, qkv, N3_, D_, N3_/256);
        rope_apply3<<<dim3(B_*S_), 256, 0, stream>>>(qkv);
        attn<<<dim3(512), 512, 0, stream>>>(qkv);
        gemm256<float><<<dim3((D_/256)*(M_/256)), 512, 0, stream>>>(
            qkv, N3_, wob, D_, bo, out, D_, D_, D_/256);
    } else {
        // compact path: fp32 inputs converted during GEMM staging; 96 MiB workspace
        gemm_bt<float,float,bf16><<<dim3(N3_/128, M_/128), 256, 0, stream>>>(
            x, D_, Wqkv, D_, bqkv, qkv, N3_, D_);
        rope_apply3<<<dim3(B_*S_), 256, 0, stream>>>(qkv);
        attn<<<dim3(512), 512, 0, stream>>>(qkv);
        gemm_bt<bf16,float,float><<<dim3(D_/128, M_/128), 256, 0, stream>>>(
            qkv, N3_, Wo, D_, bo, out, D_, D_);
    }
}